// Round 15
// baseline (219.993 us; speedup 1.0000x reference)
//
#include <hip/hip_runtime.h>

namespace {

constexpr int S_LEN = 2048;
constexpr int H_N   = 8;
constexpr int D_DIM = 64;
constexpr int N_DIM = 32;
constexpr int TW    = 32;             // timesteps per chunk
constexpr int NKC   = S_LEN / TW;     // 64 chunks per (b,h)
constexpr int SEGL  = NKC / 4;        // 16 chunks per K2 segment
constexpr float NLOG2E = -1.4426950408889634f;

// ws (all float):
//   sdtb: [kc][ch]      64*1024    (0.25 MB) — sum of dt over chunk
//   bagg: [kc][ch][n]   64*1024*32 (8.4 MB)  — chunk b-aggregate (n contiguous)
//   pref: [kc][ch][n]   64*1024*32 (8.4 MB)  — state entering chunk
// K1/K3: block = bh*64 + kc, 512 threads = 8 waves = ONE chunk. 32 waves/CU.
//   wave w: d = w*8 + (lane&7); nq = lane>>3 (8 groups); thread owns n in
//   [nq*4, nq*4+4). B (and C) staged ONCE per block into shared LDS slab
//   (one barrier); inner-loop read = one ds_read_b128 per thread per t.
//   y reduced across nq via shfl_xor 8/16/32; lanes nq==0 store.
// K2: thread = (ch, n, seg); 4 segments of 16 chunks, register scan +
//   4-lane shuffle composition.

__global__ __launch_bounds__(512, 8) void ssm_k1(
    const float* __restrict__ dtp, const float* __restrict__ up,
    const float* __restrict__ Ap,  const float* __restrict__ Bp,
    float* __restrict__ sdtb, float* __restrict__ bagg)
{
    __shared__ float lB[TW * 32];         // 4 KB shared B slab

    const int tid  = threadIdx.x;
    const int w    = tid >> 6;
    const int lane = tid & 63;
    const int dl   = lane & 7;
    const int nq   = lane >> 3;
    const int bh   = blockIdx.x >> 6;
    const int kc   = blockIdx.x & 63;
    const int b = bh >> 3, hh = bh & 7;
    const int d  = w * 8 + dl;
    const int n0 = nq * 4;
    const int ch = bh * 64 + d;
    const int s0 = kc * TW;

    const int base_ud = b * (S_LEN * 512) + hh * 64 + d;
    const int bB      = b * (S_LEN * 256) + hh * 32 + s0 * 256;

    // ---- cooperative stage: B slab (32 t x 32 n), 256 float4s ----
    if (tid < 256) {
        const int row = tid >> 3, col = tid & 7;
        *(float4*)&lB[row * 32 + col * 4] =
            *(const float4*)(Bp + bB + row * 256 + col * 4);
    }

    float Aneg[4];
    {
        float4 a4 = *(const float4*)(Ap + (hh * D_DIM + d) * N_DIM + n0);
        Aneg[0] = NLOG2E * a4.x; Aneg[1] = NLOG2E * a4.y;
        Aneg[2] = NLOG2E * a4.z; Aneg[3] = NLOG2E * a4.w;
    }

    __syncthreads();

    float bA[4] = {0.0f, 0.0f, 0.0f, 0.0f};
    float sdt = 0.0f;

#pragma unroll
    for (int st = 0; st < 8; ++st) {
        float dtv[4], uv[4];
#pragma unroll
        for (int t2 = 0; t2 < 4; ++t2) {
            const int s = s0 + st * 4 + t2;
            dtv[t2] = dtp[base_ud + s * 512];
            uv[t2]  = up [base_ud + s * 512];
        }
#pragma unroll
        for (int t2 = 0; t2 < 4; ++t2) {
            const int tt = st * 4 + t2;
            const float kk = dtv[t2] * uv[t2];
            sdt += dtv[t2];
            const float4 Bv = *(const float4*)&lB[tt * 32 + n0];
#pragma unroll
            for (int q = 0; q < 4; ++q) {
                const float bq = (q == 0) ? Bv.x : (q == 1) ? Bv.y : (q == 2) ? Bv.z : Bv.w;
                const float e = __builtin_amdgcn_exp2f(dtv[t2] * Aneg[q]);
                bA[q] = fmaf(e, bA[q], kk * bq);
            }
        }
    }

    if (nq == 0) sdtb[kc * 1024 + ch] = sdt;
    *(float4*)(bagg + (size_t)kc * 32768 + ch * 32 + n0) =
        make_float4(bA[0], bA[1], bA[2], bA[3]);
}

__global__ __launch_bounds__(256) void ssm_k2(
    const float* __restrict__ sdtb, const float* __restrict__ bagg,
    const float* __restrict__ Ap,   float* __restrict__ pref)
{
    const int T   = blockIdx.x * 256 + threadIdx.x;   // 131072 threads = (ch, n, seg)
    const int seg = T & 3;
    const int n   = (T >> 2) & 31;
    const int ch  = T >> 7;
    const int d   = ch & 63;
    const int hh  = (ch >> 6) & 7;
    const float Aneg1 = NLOG2E * Ap[(hh * D_DIM + d) * N_DIM + n];

    const int k0 = seg * SEGL;
    const size_t base = (size_t)ch * 32 + n;

    float bb[SEGL], av[SEGL];
#pragma unroll
    for (int i = 0; i < SEGL; ++i) {
        bb[i] = bagg[(size_t)(k0 + i) * 32768 + base];
        av[i] = sdtb[(k0 + i) * 1024 + ch];
    }
#pragma unroll
    for (int i = 0; i < SEGL; ++i)
        av[i] = __builtin_amdgcn_exp2f(Aneg1 * av[i]);

    float bseg = 0.0f, Aseg = 1.0f;
#pragma unroll
    for (int i = 0; i < SEGL; ++i) {
        bseg = fmaf(av[i], bseg, bb[i]);
        Aseg *= av[i];
    }

    {
        float Au = __shfl_up(Aseg, 1, 4), bu = __shfl_up(bseg, 1, 4);
        if (seg >= 1) { bseg = fmaf(Aseg, bu, bseg); Aseg *= Au; }
        Au = __shfl_up(Aseg, 2, 4); bu = __shfl_up(bseg, 2, 4);
        if (seg >= 2) { bseg = fmaf(Aseg, bu, bseg); Aseg *= Au; }
    }
    const float ebu = __shfl_up(bseg, 1, 4);
    float p = (seg == 0) ? 0.0f : ebu;

#pragma unroll
    for (int i = 0; i < SEGL; ++i) {
        pref[(size_t)(k0 + i) * 32768 + base] = p;
        p = fmaf(av[i], p, bb[i]);
    }
}

__global__ __launch_bounds__(512, 8) void ssm_k3(
    const float* __restrict__ dtp, const float* __restrict__ up,
    const float* __restrict__ Ap,  const float* __restrict__ Bp,
    const float* __restrict__ Cp,  const float* __restrict__ Dp,
    const float* __restrict__ pref, float* __restrict__ outp)
{
    __shared__ float lB[TW * 32];         // 4 KB
    __shared__ float lC[TW * 32];         // 4 KB

    const int tid  = threadIdx.x;
    const int w    = tid >> 6;
    const int lane = tid & 63;
    const int dl   = lane & 7;
    const int nq   = lane >> 3;
    const int bh   = blockIdx.x >> 6;
    const int kc   = blockIdx.x & 63;
    const int b = bh >> 3, hh = bh & 7;
    const int d  = w * 8 + dl;
    const int n0 = nq * 4;
    const int ch = bh * 64 + d;
    const int s0 = kc * TW;

    const int base_ud = b * (S_LEN * 512) + hh * 64 + d;
    const int bB      = b * (S_LEN * 256) + hh * 32 + s0 * 256;

    // ---- cooperative stage: B (tid<256) and C (tid>=256) slabs ----
    {
        const int t8 = tid & 255;
        const int row = t8 >> 3, col = t8 & 7;
        if (tid < 256) {
            *(float4*)&lB[row * 32 + col * 4] =
                *(const float4*)(Bp + bB + row * 256 + col * 4);
        } else {
            *(float4*)&lC[row * 32 + col * 4] =
                *(const float4*)(Cp + bB + row * 256 + col * 4);
        }
    }

    // ---- entering state: one float4 ----
    float h[4];
    {
        float4 v = *(const float4*)(pref + (size_t)kc * 32768 + ch * 32 + n0);
        h[0] = v.x; h[1] = v.y; h[2] = v.z; h[3] = v.w;
    }

    float Aneg[4];
    {
        float4 a4 = *(const float4*)(Ap + (hh * D_DIM + d) * N_DIM + n0);
        Aneg[0] = NLOG2E * a4.x; Aneg[1] = NLOG2E * a4.y;
        Aneg[2] = NLOG2E * a4.z; Aneg[3] = NLOG2E * a4.w;
    }

    const float Dv = Dp[hh];

    __syncthreads();

#pragma unroll
    for (int st = 0; st < 8; ++st) {
        float dtv[4], uv[4];
#pragma unroll
        for (int t2 = 0; t2 < 4; ++t2) {
            const int s = s0 + st * 4 + t2;
            dtv[t2] = dtp[base_ud + s * 512];
            uv[t2]  = up [base_ud + s * 512];
        }
#pragma unroll
        for (int t2 = 0; t2 < 4; ++t2) {
            const int tt = st * 4 + t2;
            const float kk = dtv[t2] * uv[t2];
            const float4 Bv = *(const float4*)&lB[tt * 32 + n0];
            const float4 Cv = *(const float4*)&lC[tt * 32 + n0];
            float y0 = 0.0f, y1 = 0.0f;
#pragma unroll
            for (int q = 0; q < 4; ++q) {
                const float bq = (q == 0) ? Bv.x : (q == 1) ? Bv.y : (q == 2) ? Bv.z : Bv.w;
                const float cq = (q == 0) ? Cv.x : (q == 1) ? Cv.y : (q == 2) ? Cv.z : Cv.w;
                const float e = __builtin_amdgcn_exp2f(dtv[t2] * Aneg[q]);
                h[q] = fmaf(e, h[q], kk * bq);
                if (q & 1) y1 = fmaf(h[q], cq, y1);
                else       y0 = fmaf(h[q], cq, y0);
            }
            float y = y0 + y1;
            y += __shfl_xor(y, 8);
            y += __shfl_xor(y, 16);
            y += __shfl_xor(y, 32);
            if (nq == 0) outp[base_ud + (s0 + tt) * 512] = fmaf(Dv, uv[t2], y);
        }
    }
}

} // namespace

extern "C" void kernel_launch(void* const* d_in, const int* in_sizes, int n_in,
                              void* d_out, int out_size, void* d_ws, size_t ws_size,
                              hipStream_t stream)
{
    const float* u  = (const float*)d_in[0];
    const float* dt = (const float*)d_in[1];
    const float* A  = (const float*)d_in[2];
    const float* B  = (const float*)d_in[3];
    const float* C  = (const float*)d_in[4];
    const float* D  = (const float*)d_in[5];
    float* out = (float*)d_out;

    float* sdtb = (float*)d_ws;                         // 0.25 MB
    float* bagg = sdtb + (size_t)NKC * 1024;            // 8.4 MB
    float* pref = bagg + (size_t)NKC * 32 * 1024;       // 8.4 MB

    ssm_k1<<<dim3(16 * NKC), dim3(512), 0, stream>>>(dt, u, A, B, sdtb, bagg);
    ssm_k2<<<dim3(512),      dim3(256), 0, stream>>>(sdtb, bagg, A, pref);
    ssm_k3<<<dim3(16 * NKC), dim3(512), 0, stream>>>(dt, u, A, B, C, D, pref, out);
}

// Round 16
// 48.890 us; speedup vs baseline: 4.4997x; 4.4997x over previous
//
#include <hip/hip_runtime.h>

namespace {

constexpr int S_LEN = 2048;
constexpr int H_N   = 8;
constexpr int D_DIM = 64;
constexpr int N_DIM = 32;
constexpr int TW    = 32;             // timesteps per chunk
constexpr int NKC   = S_LEN / TW;     // 64 chunks per (b,h)
constexpr int SEGL  = NKC / 4;        // 16 chunks per K2 segment
constexpr float NLOG2E = -1.4426950408889634f;

// ws (all float):
//   sdtb: [kc][ch]      64*1024    (0.25 MB) — sum of dt over chunk
//   bagg: [kc][ch][n]   64*1024*32 (8.4 MB)  — chunk b-aggregate (n contiguous)
//   pref: [kc][ch][n]   64*1024*32 (8.4 MB)  — state entering chunk
// K1/K3: block = bh*64 + kc, 512 threads = 8 waves = ONE chunk.
//   wave w: d = w*8 + (lane&7); nq = lane>>3 (8 groups); thread owns n in
//   [nq*4, nq*4+4). B (and C) staged once per block (one barrier).
//   NOTE: no min-waves launch_bounds — R15's (512,8) forced VGPR=32 and
//   produced 650 MB of scratch-spill HBM traffic (200 µs). Natural VGPR
//   ~50 <= 64 gives 8 waves/EU organically (occupancy halves at 64 VGPR).
// K2: thread = (ch, n, seg); 4 segments of 16 chunks, register scan +
//   4-lane shuffle composition.

__global__ __launch_bounds__(512) void ssm_k1(
    const float* __restrict__ dtp, const float* __restrict__ up,
    const float* __restrict__ Ap,  const float* __restrict__ Bp,
    float* __restrict__ sdtb, float* __restrict__ bagg)
{
    __shared__ float lB[TW * 32];         // 4 KB shared B slab

    const int tid  = threadIdx.x;
    const int w    = tid >> 6;
    const int lane = tid & 63;
    const int dl   = lane & 7;
    const int nq   = lane >> 3;
    const int bh   = blockIdx.x >> 6;
    const int kc   = blockIdx.x & 63;
    const int b = bh >> 3, hh = bh & 7;
    const int d  = w * 8 + dl;
    const int n0 = nq * 4;
    const int ch = bh * 64 + d;
    const int s0 = kc * TW;

    const int base_ud = b * (S_LEN * 512) + hh * 64 + d;
    const int bB      = b * (S_LEN * 256) + hh * 32 + s0 * 256;

    // ---- cooperative stage: B slab (32 t x 32 n), 256 float4s ----
    if (tid < 256) {
        const int row = tid >> 3, col = tid & 7;
        *(float4*)&lB[row * 32 + col * 4] =
            *(const float4*)(Bp + bB + row * 256 + col * 4);
    }

    float Aneg[4];
    {
        float4 a4 = *(const float4*)(Ap + (hh * D_DIM + d) * N_DIM + n0);
        Aneg[0] = NLOG2E * a4.x; Aneg[1] = NLOG2E * a4.y;
        Aneg[2] = NLOG2E * a4.z; Aneg[3] = NLOG2E * a4.w;
    }

    __syncthreads();

    float bA[4] = {0.0f, 0.0f, 0.0f, 0.0f};
    float sdt = 0.0f;

#pragma unroll
    for (int st = 0; st < 8; ++st) {
        float dtv[4], uv[4];
#pragma unroll
        for (int t2 = 0; t2 < 4; ++t2) {
            const int s = s0 + st * 4 + t2;
            dtv[t2] = dtp[base_ud + s * 512];
            uv[t2]  = up [base_ud + s * 512];
        }
#pragma unroll
        for (int t2 = 0; t2 < 4; ++t2) {
            const int tt = st * 4 + t2;
            const float kk = dtv[t2] * uv[t2];
            sdt += dtv[t2];
            const float4 Bv = *(const float4*)&lB[tt * 32 + n0];
#pragma unroll
            for (int q = 0; q < 4; ++q) {
                const float bq = (q == 0) ? Bv.x : (q == 1) ? Bv.y : (q == 2) ? Bv.z : Bv.w;
                const float e = __builtin_amdgcn_exp2f(dtv[t2] * Aneg[q]);
                bA[q] = fmaf(e, bA[q], kk * bq);
            }
        }
    }

    if (nq == 0) sdtb[kc * 1024 + ch] = sdt;
    *(float4*)(bagg + (size_t)kc * 32768 + ch * 32 + n0) =
        make_float4(bA[0], bA[1], bA[2], bA[3]);
}

__global__ __launch_bounds__(256) void ssm_k2(
    const float* __restrict__ sdtb, const float* __restrict__ bagg,
    const float* __restrict__ Ap,   float* __restrict__ pref)
{
    const int T   = blockIdx.x * 256 + threadIdx.x;   // 131072 threads = (ch, n, seg)
    const int seg = T & 3;
    const int n   = (T >> 2) & 31;
    const int ch  = T >> 7;
    const int d   = ch & 63;
    const int hh  = (ch >> 6) & 7;
    const float Aneg1 = NLOG2E * Ap[(hh * D_DIM + d) * N_DIM + n];

    const int k0 = seg * SEGL;
    const size_t base = (size_t)ch * 32 + n;

    float bb[SEGL], av[SEGL];
#pragma unroll
    for (int i = 0; i < SEGL; ++i) {
        bb[i] = bagg[(size_t)(k0 + i) * 32768 + base];
        av[i] = sdtb[(k0 + i) * 1024 + ch];
    }
#pragma unroll
    for (int i = 0; i < SEGL; ++i)
        av[i] = __builtin_amdgcn_exp2f(Aneg1 * av[i]);

    float bseg = 0.0f, Aseg = 1.0f;
#pragma unroll
    for (int i = 0; i < SEGL; ++i) {
        bseg = fmaf(av[i], bseg, bb[i]);
        Aseg *= av[i];
    }

    {
        float Au = __shfl_up(Aseg, 1, 4), bu = __shfl_up(bseg, 1, 4);
        if (seg >= 1) { bseg = fmaf(Aseg, bu, bseg); Aseg *= Au; }
        Au = __shfl_up(Aseg, 2, 4); bu = __shfl_up(bseg, 2, 4);
        if (seg >= 2) { bseg = fmaf(Aseg, bu, bseg); Aseg *= Au; }
    }
    const float ebu = __shfl_up(bseg, 1, 4);
    float p = (seg == 0) ? 0.0f : ebu;

#pragma unroll
    for (int i = 0; i < SEGL; ++i) {
        pref[(size_t)(k0 + i) * 32768 + base] = p;
        p = fmaf(av[i], p, bb[i]);
    }
}

__global__ __launch_bounds__(512) void ssm_k3(
    const float* __restrict__ dtp, const float* __restrict__ up,
    const float* __restrict__ Ap,  const float* __restrict__ Bp,
    const float* __restrict__ Cp,  const float* __restrict__ Dp,
    const float* __restrict__ pref, float* __restrict__ outp)
{
    __shared__ float lB[TW * 32];         // 4 KB
    __shared__ float lC[TW * 32];         // 4 KB

    const int tid  = threadIdx.x;
    const int w    = tid >> 6;
    const int lane = tid & 63;
    const int dl   = lane & 7;
    const int nq   = lane >> 3;
    const int bh   = blockIdx.x >> 6;
    const int kc   = blockIdx.x & 63;
    const int b = bh >> 3, hh = bh & 7;
    const int d  = w * 8 + dl;
    const int n0 = nq * 4;
    const int ch = bh * 64 + d;
    const int s0 = kc * TW;

    const int base_ud = b * (S_LEN * 512) + hh * 64 + d;
    const int bB      = b * (S_LEN * 256) + hh * 32 + s0 * 256;

    // ---- cooperative stage: B (tid<256) and C (tid>=256) slabs ----
    {
        const int t8 = tid & 255;
        const int row = t8 >> 3, col = t8 & 7;
        if (tid < 256) {
            *(float4*)&lB[row * 32 + col * 4] =
                *(const float4*)(Bp + bB + row * 256 + col * 4);
        } else {
            *(float4*)&lC[row * 32 + col * 4] =
                *(const float4*)(Cp + bB + row * 256 + col * 4);
        }
    }

    // ---- entering state: one float4 ----
    float h[4];
    {
        float4 v = *(const float4*)(pref + (size_t)kc * 32768 + ch * 32 + n0);
        h[0] = v.x; h[1] = v.y; h[2] = v.z; h[3] = v.w;
    }

    float Aneg[4];
    {
        float4 a4 = *(const float4*)(Ap + (hh * D_DIM + d) * N_DIM + n0);
        Aneg[0] = NLOG2E * a4.x; Aneg[1] = NLOG2E * a4.y;
        Aneg[2] = NLOG2E * a4.z; Aneg[3] = NLOG2E * a4.w;
    }

    const float Dv = Dp[hh];

    __syncthreads();

#pragma unroll
    for (int st = 0; st < 8; ++st) {
        float dtv[4], uv[4];
#pragma unroll
        for (int t2 = 0; t2 < 4; ++t2) {
            const int s = s0 + st * 4 + t2;
            dtv[t2] = dtp[base_ud + s * 512];
            uv[t2]  = up [base_ud + s * 512];
        }
#pragma unroll
        for (int t2 = 0; t2 < 4; ++t2) {
            const int tt = st * 4 + t2;
            const float kk = dtv[t2] * uv[t2];
            const float4 Bv = *(const float4*)&lB[tt * 32 + n0];
            const float4 Cv = *(const float4*)&lC[tt * 32 + n0];
            float y0 = 0.0f, y1 = 0.0f;
#pragma unroll
            for (int q = 0; q < 4; ++q) {
                const float bq = (q == 0) ? Bv.x : (q == 1) ? Bv.y : (q == 2) ? Bv.z : Bv.w;
                const float cq = (q == 0) ? Cv.x : (q == 1) ? Cv.y : (q == 2) ? Cv.z : Cv.w;
                const float e = __builtin_amdgcn_exp2f(dtv[t2] * Aneg[q]);
                h[q] = fmaf(e, h[q], kk * bq);
                if (q & 1) y1 = fmaf(h[q], cq, y1);
                else       y0 = fmaf(h[q], cq, y0);
            }
            float y = y0 + y1;
            y += __shfl_xor(y, 8);
            y += __shfl_xor(y, 16);
            y += __shfl_xor(y, 32);
            if (nq == 0) outp[base_ud + (s0 + tt) * 512] = fmaf(Dv, uv[t2], y);
        }
    }
}

} // namespace

extern "C" void kernel_launch(void* const* d_in, const int* in_sizes, int n_in,
                              void* d_out, int out_size, void* d_ws, size_t ws_size,
                              hipStream_t stream)
{
    const float* u  = (const float*)d_in[0];
    const float* dt = (const float*)d_in[1];
    const float* A  = (const float*)d_in[2];
    const float* B  = (const float*)d_in[3];
    const float* C  = (const float*)d_in[4];
    const float* D  = (const float*)d_in[5];
    float* out = (float*)d_out;

    float* sdtb = (float*)d_ws;                         // 0.25 MB
    float* bagg = sdtb + (size_t)NKC * 1024;            // 8.4 MB
    float* pref = bagg + (size_t)NKC * 32 * 1024;       // 8.4 MB

    ssm_k1<<<dim3(16 * NKC), dim3(512), 0, stream>>>(dt, u, A, B, sdtb, bagg);
    ssm_k2<<<dim3(512),      dim3(256), 0, stream>>>(sdtb, bagg, A, pref);
    ssm_k3<<<dim3(16 * NKC), dim3(512), 0, stream>>>(dt, u, A, B, C, D, pref, out);
}

// Round 17
// 45.544 us; speedup vs baseline: 4.8303x; 1.0735x over previous
//
#include <hip/hip_runtime.h>

namespace {

constexpr int S_LEN = 2048;
constexpr int H_N   = 8;
constexpr int D_DIM = 64;
constexpr int N_DIM = 32;
constexpr int TW    = 64;             // timesteps per chunk
constexpr int NKC   = S_LEN / TW;     // 32 chunks per (b,h)
constexpr int NSEG  = 8;
constexpr int SEGL  = NKC / NSEG;     // 4 chunks per K2 segment
constexpr float NLOG2E = -1.4426950408889634f;

// ws (all float):
//   sdtb: [kc][ch]      32*1024    (0.13 MB) — sum of dt over chunk
//   bagg: [kc][ch][n]   32*1024*32 (4.2 MB)  — chunk b-aggregate (n contiguous)
//   pref: [kc][ch][n]   32*1024*32 (4.2 MB)  — state entering chunk
// K1/K3: block = bh*32 + kc (256 thr = 4 waves, ONE chunk per block).
//   wave w: d = w*16 + (lane&15); nq = lane>>4; n0 = nq*8 (8 n per thread).
//   Barrier-free: per-wave private B/C LDS slabs (8 KB each), dt/u in regs
//   via 4 sub-tiles of 16 steps. 512 blocks -> 8 waves/CU (tests TLP vs
//   per-chunk-overhead tradeoff; R16 falsified >16 w/CU helping).
// K2: thread = (ch, n, seg); 8 segments of 4 chunks, register scan +
//   8-lane shuffle composition (4096 waves).

__global__ __launch_bounds__(256) void ssm_k1(
    const float* __restrict__ dtp, const float* __restrict__ up,
    const float* __restrict__ Ap,  const float* __restrict__ Bp,
    float* __restrict__ sdtb, float* __restrict__ bagg)
{
    __shared__ float lB[4][TW * 32];      // per-wave B slab (8 KB each)

    const int tid  = threadIdx.x;
    const int w    = tid >> 6;
    const int lane = tid & 63;
    const int dl   = lane & 15;
    const int nq   = lane >> 4;
    const int bh   = blockIdx.x >> 5;
    const int kc   = blockIdx.x & 31;
    const int b = bh >> 3, hh = bh & 7;
    const int d  = w * 16 + dl;
    const int n0 = nq * 8;
    const int ch = bh * 64 + d;
    const int s0 = kc * TW;

    const int base_ud = b * (S_LEN * 512) + hh * 64 + d;
    const int bB      = b * (S_LEN * 256) + hh * 32 + s0 * 256;

    // ---- per-wave stage: B slab (64 t x 32 n) = 512 float4s ----
#pragma unroll
    for (int it = 0; it < 8; ++it) {
        const int idx = it * 64 + lane;
        const int row = idx >> 3, col = idx & 7;
        *(float4*)&lB[w][idx * 4] = *(const float4*)(Bp + bB + row * 256 + col * 4);
    }

    float Aneg[8];
    {
        const float* Arow = Ap + (hh * D_DIM + d) * N_DIM + n0;
#pragma unroll
        for (int j = 0; j < 2; ++j) {
            float4 a4 = *(const float4*)(Arow + j * 4);
            Aneg[4*j+0] = NLOG2E * a4.x; Aneg[4*j+1] = NLOG2E * a4.y;
            Aneg[4*j+2] = NLOG2E * a4.z; Aneg[4*j+3] = NLOG2E * a4.w;
        }
    }

    float bA[8] = {0,0,0,0,0,0,0,0};
    float sdt = 0.0f;

#pragma unroll
    for (int st = 0; st < 4; ++st) {
        float dtv[16], uv[16];
#pragma unroll
        for (int t2 = 0; t2 < 16; ++t2) {
            const int s = s0 + st * 16 + t2;
            dtv[t2] = dtp[base_ud + s * 512];
            uv[t2]  = up [base_ud + s * 512];
        }
#pragma unroll 4
        for (int t2 = 0; t2 < 16; ++t2) {
            const int tt = st * 16 + t2;
            const float kk = dtv[t2] * uv[t2];
            sdt += dtv[t2];
#pragma unroll
            for (int j = 0; j < 2; ++j) {
                const float4 Bv = *(const float4*)&lB[w][tt * 32 + n0 + j * 4];
#pragma unroll
                for (int q = 0; q < 4; ++q) {
                    const int jn = j * 4 + q;
                    const float bq = (q == 0) ? Bv.x : (q == 1) ? Bv.y : (q == 2) ? Bv.z : Bv.w;
                    const float e = __builtin_amdgcn_exp2f(dtv[t2] * Aneg[jn]);
                    bA[jn] = fmaf(e, bA[jn], kk * bq);
                }
            }
        }
    }

    if (nq == 0) sdtb[kc * 1024 + ch] = sdt;
    {
        float* dst = bagg + (size_t)kc * 32768 + ch * 32 + n0;
        *(float4*)(dst + 0) = make_float4(bA[0], bA[1], bA[2], bA[3]);
        *(float4*)(dst + 4) = make_float4(bA[4], bA[5], bA[6], bA[7]);
    }
}

__global__ __launch_bounds__(256) void ssm_k2(
    const float* __restrict__ sdtb, const float* __restrict__ bagg,
    const float* __restrict__ Ap,   float* __restrict__ pref)
{
    const int T   = blockIdx.x * 256 + threadIdx.x;   // 262144 threads = (ch, n, seg)
    const int seg = T & 7;
    const int n   = (T >> 3) & 31;
    const int ch  = T >> 8;
    const int d   = ch & 63;
    const int hh  = (ch >> 6) & 7;
    const float Aneg1 = NLOG2E * Ap[(hh * D_DIM + d) * N_DIM + n];

    const int k0 = seg * SEGL;
    const size_t base = (size_t)ch * 32 + n;

    float bb[SEGL], av[SEGL];
#pragma unroll
    for (int i = 0; i < SEGL; ++i) {
        bb[i] = bagg[(size_t)(k0 + i) * 32768 + base];
        av[i] = sdtb[(k0 + i) * 1024 + ch];
    }
#pragma unroll
    for (int i = 0; i < SEGL; ++i)
        av[i] = __builtin_amdgcn_exp2f(Aneg1 * av[i]);

    float bseg = 0.0f, Aseg = 1.0f;
#pragma unroll
    for (int i = 0; i < SEGL; ++i) {
        bseg = fmaf(av[i], bseg, bb[i]);
        Aseg *= av[i];
    }

    // 8-lane inclusive composition scan (width 8), then exclusive shift
    {
        float Au = __shfl_up(Aseg, 1, 8), bu = __shfl_up(bseg, 1, 8);
        if (seg >= 1) { bseg = fmaf(Aseg, bu, bseg); Aseg *= Au; }
        Au = __shfl_up(Aseg, 2, 8); bu = __shfl_up(bseg, 2, 8);
        if (seg >= 2) { bseg = fmaf(Aseg, bu, bseg); Aseg *= Au; }
        Au = __shfl_up(Aseg, 4, 8); bu = __shfl_up(bseg, 4, 8);
        if (seg >= 4) { bseg = fmaf(Aseg, bu, bseg); Aseg *= Au; }
    }
    const float ebu = __shfl_up(bseg, 1, 8);
    float p = (seg == 0) ? 0.0f : ebu;

#pragma unroll
    for (int i = 0; i < SEGL; ++i) {
        pref[(size_t)(k0 + i) * 32768 + base] = p;
        p = fmaf(av[i], p, bb[i]);
    }
}

__global__ __launch_bounds__(256) void ssm_k3(
    const float* __restrict__ dtp, const float* __restrict__ up,
    const float* __restrict__ Ap,  const float* __restrict__ Bp,
    const float* __restrict__ Cp,  const float* __restrict__ Dp,
    const float* __restrict__ pref, float* __restrict__ outp)
{
    __shared__ float lB[4][TW * 32];      // 8 KB per wave
    __shared__ float lC[4][TW * 32];      // 8 KB per wave

    const int tid  = threadIdx.x;
    const int w    = tid >> 6;
    const int lane = tid & 63;
    const int dl   = lane & 15;
    const int nq   = lane >> 4;
    const int bh   = blockIdx.x >> 5;
    const int kc   = blockIdx.x & 31;
    const int b = bh >> 3, hh = bh & 7;
    const int d  = w * 16 + dl;
    const int n0 = nq * 8;
    const int ch = bh * 64 + d;
    const int s0 = kc * TW;

    const int base_ud = b * (S_LEN * 512) + hh * 64 + d;
    const int bB      = b * (S_LEN * 256) + hh * 32 + s0 * 256;

    // ---- entering state: 2 contiguous float4 loads ----
    float h[8];
    {
        const float* ps = pref + (size_t)kc * 32768 + ch * 32 + n0;
        float4 v0 = *(const float4*)(ps + 0);
        float4 v1 = *(const float4*)(ps + 4);
        h[0] = v0.x; h[1] = v0.y; h[2] = v0.z; h[3] = v0.w;
        h[4] = v1.x; h[5] = v1.y; h[6] = v1.z; h[7] = v1.w;
    }

    // ---- per-wave stage: B and C slabs ----
#pragma unroll
    for (int it = 0; it < 8; ++it) {
        const int idx = it * 64 + lane;
        const int row = idx >> 3, col = idx & 7;
        *(float4*)&lB[w][idx * 4] = *(const float4*)(Bp + bB + row * 256 + col * 4);
        *(float4*)&lC[w][idx * 4] = *(const float4*)(Cp + bB + row * 256 + col * 4);
    }

    float Aneg[8];
    {
        const float* Arow = Ap + (hh * D_DIM + d) * N_DIM + n0;
#pragma unroll
        for (int j = 0; j < 2; ++j) {
            float4 a4 = *(const float4*)(Arow + j * 4);
            Aneg[4*j+0] = NLOG2E * a4.x; Aneg[4*j+1] = NLOG2E * a4.y;
            Aneg[4*j+2] = NLOG2E * a4.z; Aneg[4*j+3] = NLOG2E * a4.w;
        }
    }

    const float Dv = Dp[hh];

#pragma unroll
    for (int st = 0; st < 4; ++st) {
        float dtv[16], uv[16];
#pragma unroll
        for (int t2 = 0; t2 < 16; ++t2) {
            const int s = s0 + st * 16 + t2;
            dtv[t2] = dtp[base_ud + s * 512];
            uv[t2]  = up [base_ud + s * 512];
        }
#pragma unroll 4
        for (int t2 = 0; t2 < 16; ++t2) {
            const int tt = st * 16 + t2;
            const float kk = dtv[t2] * uv[t2];
            float y0 = 0.0f, y1 = 0.0f, y2 = 0.0f, y3 = 0.0f;
#pragma unroll
            for (int j = 0; j < 2; ++j) {
                const float4 Bv = *(const float4*)&lB[w][tt * 32 + n0 + j * 4];
                const float4 Cv = *(const float4*)&lC[w][tt * 32 + n0 + j * 4];
#pragma unroll
                for (int q = 0; q < 4; ++q) {
                    const int jn = j * 4 + q;
                    const float bq = (q == 0) ? Bv.x : (q == 1) ? Bv.y : (q == 2) ? Bv.z : Bv.w;
                    const float cq = (q == 0) ? Cv.x : (q == 1) ? Cv.y : (q == 2) ? Cv.z : Cv.w;
                    const float e = __builtin_amdgcn_exp2f(dtv[t2] * Aneg[jn]);
                    h[jn] = fmaf(e, h[jn], kk * bq);
                    if (q == 0)      y0 = fmaf(h[jn], cq, y0);
                    else if (q == 1) y1 = fmaf(h[jn], cq, y1);
                    else if (q == 2) y2 = fmaf(h[jn], cq, y2);
                    else             y3 = fmaf(h[jn], cq, y3);
                }
            }
            float y = (y0 + y1) + (y2 + y3);
            y += __shfl_xor(y, 16);
            y += __shfl_xor(y, 32);
            if (nq == 0) outp[base_ud + (s0 + tt) * 512] = fmaf(Dv, uv[t2], y);
        }
    }
}

} // namespace

extern "C" void kernel_launch(void* const* d_in, const int* in_sizes, int n_in,
                              void* d_out, int out_size, void* d_ws, size_t ws_size,
                              hipStream_t stream)
{
    const float* u  = (const float*)d_in[0];
    const float* dt = (const float*)d_in[1];
    const float* A  = (const float*)d_in[2];
    const float* B  = (const float*)d_in[3];
    const float* C  = (const float*)d_in[4];
    const float* D  = (const float*)d_in[5];
    float* out = (float*)d_out;

    float* sdtb = (float*)d_ws;                         // 0.13 MB
    float* bagg = sdtb + (size_t)NKC * 1024;            // 4.2 MB
    float* pref = bagg + (size_t)NKC * 32 * 1024;       // 4.2 MB

    ssm_k1<<<dim3(16 * NKC), dim3(256), 0, stream>>>(dt, u, A, B, sdtb, bagg);
    ssm_k2<<<dim3(1024),     dim3(256), 0, stream>>>(sdtb, bagg, A, pref);
    ssm_k3<<<dim3(16 * NKC), dim3(256), 0, stream>>>(dt, u, A, B, C, D, pref, out);
}

// Round 18
// 44.067 us; speedup vs baseline: 4.9923x; 1.0335x over previous
//
#include <hip/hip_runtime.h>

namespace {

constexpr int S_LEN = 2048;
constexpr int H_N   = 8;
constexpr int D_DIM = 64;
constexpr int N_DIM = 32;
constexpr int TW    = 32;             // timesteps per chunk
constexpr int NKC   = S_LEN / TW;     // 64 chunks per (b,h)
constexpr int SEGL  = NKC / 4;        // 16 chunks per K2 segment
constexpr float NLOG2E = -1.4426950408889634f;

// ws (all float):
//   sdtb: [kc][ch]      64*1024    (0.25 MB) — sum of dt over chunk
//   bagg: [kc][ch][n]   64*1024*32 (8.4 MB)  — chunk b-aggregate (n contiguous)
//   pref: [kc][ch][n]   64*1024*32 (8.4 MB)  — state entering chunk
// K1/K3: block = bh*64 + kc (256 thr = 4 waves, ONE chunk per block).
//   wave w = d-quarter: d = w*16 + (lane&15); nq = lane>>4; n0 = nq*8.
//   Thread owns 8 n's. B (and C in K3) staged ONCE per block cooperatively
//   (each thread exactly one float4 per slab) + one __syncthreads — R13 had
//   4x duplicated per-wave staging; this removes it at the cost of 1 barrier.
//   dt/u prefetched to regs in two 16-step sub-tiles (unchanged from R13).
// K2: thread = (ch, n, seg); 4 segments of 16 chunks, register scan +
//   4-lane shuffle composition (2048 waves).

__global__ __launch_bounds__(256) void ssm_k1(
    const float* __restrict__ dtp, const float* __restrict__ up,
    const float* __restrict__ Ap,  const float* __restrict__ Bp,
    float* __restrict__ sdtb, float* __restrict__ bagg)
{
    __shared__ float lB[TW * 32];         // 4 KB shared B slab (single copy)

    const int tid  = threadIdx.x;
    const int w    = tid >> 6;
    const int lane = tid & 63;
    const int dl   = lane & 15;
    const int nq   = lane >> 4;
    const int bh   = blockIdx.x >> 6;
    const int kc   = blockIdx.x & 63;
    const int b = bh >> 3, hh = bh & 7;
    const int d  = w * 16 + dl;
    const int n0 = nq * 8;
    const int ch = bh * 64 + d;
    const int s0 = kc * TW;

    const int base_ud = b * (S_LEN * 512) + hh * 64 + d;
    const int bB      = b * (S_LEN * 256) + hh * 32 + s0 * 256;

    // ---- cooperative stage: B slab (32 t x 32 n) = 256 float4s, 1 each ----
    {
        const int row = tid >> 3, col = tid & 7;
        *(float4*)&lB[row * 32 + col * 4] =
            *(const float4*)(Bp + bB + row * 256 + col * 4);
    }

    float Aneg[8];
    {
        const float* Arow = Ap + (hh * D_DIM + d) * N_DIM + n0;
#pragma unroll
        for (int j = 0; j < 2; ++j) {
            float4 a4 = *(const float4*)(Arow + j * 4);
            Aneg[4*j+0] = NLOG2E * a4.x; Aneg[4*j+1] = NLOG2E * a4.y;
            Aneg[4*j+2] = NLOG2E * a4.z; Aneg[4*j+3] = NLOG2E * a4.w;
        }
    }

    __syncthreads();

    float bA[8] = {0,0,0,0,0,0,0,0};
    float sdt = 0.0f;

#pragma unroll
    for (int st = 0; st < 2; ++st) {
        float dtv[16], uv[16];
#pragma unroll
        for (int t2 = 0; t2 < 16; ++t2) {
            const int s = s0 + st * 16 + t2;
            dtv[t2] = dtp[base_ud + s * 512];
            uv[t2]  = up [base_ud + s * 512];
        }
#pragma unroll 4
        for (int t2 = 0; t2 < 16; ++t2) {
            const int tt = st * 16 + t2;
            const float kk = dtv[t2] * uv[t2];
            sdt += dtv[t2];
#pragma unroll
            for (int j = 0; j < 2; ++j) {
                const float4 Bv = *(const float4*)&lB[tt * 32 + n0 + j * 4];
#pragma unroll
                for (int q = 0; q < 4; ++q) {
                    const int jn = j * 4 + q;
                    const float bq = (q == 0) ? Bv.x : (q == 1) ? Bv.y : (q == 2) ? Bv.z : Bv.w;
                    const float e = __builtin_amdgcn_exp2f(dtv[t2] * Aneg[jn]);
                    bA[jn] = fmaf(e, bA[jn], kk * bq);
                }
            }
        }
    }

    if (nq == 0) sdtb[kc * 1024 + ch] = sdt;
    {
        float* dst = bagg + (size_t)kc * 32768 + ch * 32 + n0;
        *(float4*)(dst + 0) = make_float4(bA[0], bA[1], bA[2], bA[3]);
        *(float4*)(dst + 4) = make_float4(bA[4], bA[5], bA[6], bA[7]);
    }
}

__global__ __launch_bounds__(256) void ssm_k2(
    const float* __restrict__ sdtb, const float* __restrict__ bagg,
    const float* __restrict__ Ap,   float* __restrict__ pref)
{
    const int T   = blockIdx.x * 256 + threadIdx.x;   // 131072 threads = (ch, n, seg)
    const int seg = T & 3;
    const int n   = (T >> 2) & 31;
    const int ch  = T >> 7;
    const int d   = ch & 63;
    const int hh  = (ch >> 6) & 7;
    const float Aneg1 = NLOG2E * Ap[(hh * D_DIM + d) * N_DIM + n];

    const int k0 = seg * SEGL;
    const size_t base = (size_t)ch * 32 + n;

    float bb[SEGL], av[SEGL];
#pragma unroll
    for (int i = 0; i < SEGL; ++i) {
        bb[i] = bagg[(size_t)(k0 + i) * 32768 + base];
        av[i] = sdtb[(k0 + i) * 1024 + ch];
    }
#pragma unroll
    for (int i = 0; i < SEGL; ++i)
        av[i] = __builtin_amdgcn_exp2f(Aneg1 * av[i]);

    float bseg = 0.0f, Aseg = 1.0f;
#pragma unroll
    for (int i = 0; i < SEGL; ++i) {
        bseg = fmaf(av[i], bseg, bb[i]);
        Aseg *= av[i];
    }

    {
        float Au = __shfl_up(Aseg, 1, 4), bu = __shfl_up(bseg, 1, 4);
        if (seg >= 1) { bseg = fmaf(Aseg, bu, bseg); Aseg *= Au; }
        Au = __shfl_up(Aseg, 2, 4); bu = __shfl_up(bseg, 2, 4);
        if (seg >= 2) { bseg = fmaf(Aseg, bu, bseg); Aseg *= Au; }
    }
    const float ebu = __shfl_up(bseg, 1, 4);
    float p = (seg == 0) ? 0.0f : ebu;

#pragma unroll
    for (int i = 0; i < SEGL; ++i) {
        pref[(size_t)(k0 + i) * 32768 + base] = p;
        p = fmaf(av[i], p, bb[i]);
    }
}

__global__ __launch_bounds__(256) void ssm_k3(
    const float* __restrict__ dtp, const float* __restrict__ up,
    const float* __restrict__ Ap,  const float* __restrict__ Bp,
    const float* __restrict__ Cp,  const float* __restrict__ Dp,
    const float* __restrict__ pref, float* __restrict__ outp)
{
    __shared__ float lB[TW * 32];         // 4 KB (single copy)
    __shared__ float lC[TW * 32];         // 4 KB (single copy)

    const int tid  = threadIdx.x;
    const int w    = tid >> 6;
    const int lane = tid & 63;
    const int dl   = lane & 15;
    const int nq   = lane >> 4;
    const int bh   = blockIdx.x >> 6;
    const int kc   = blockIdx.x & 63;
    const int b = bh >> 3, hh = bh & 7;
    const int d  = w * 16 + dl;
    const int n0 = nq * 8;
    const int ch = bh * 64 + d;
    const int s0 = kc * TW;

    const int base_ud = b * (S_LEN * 512) + hh * 64 + d;
    const int bB      = b * (S_LEN * 256) + hh * 32 + s0 * 256;

    // ---- cooperative stage: B and C slabs, one float4 each per thread ----
    {
        const int row = tid >> 3, col = tid & 7;
        *(float4*)&lB[row * 32 + col * 4] =
            *(const float4*)(Bp + bB + row * 256 + col * 4);
        *(float4*)&lC[row * 32 + col * 4] =
            *(const float4*)(Cp + bB + row * 256 + col * 4);
    }

    // ---- entering state: 2 contiguous float4 loads ----
    float h[8];
    {
        const float* ps = pref + (size_t)kc * 32768 + ch * 32 + n0;
        float4 v0 = *(const float4*)(ps + 0);
        float4 v1 = *(const float4*)(ps + 4);
        h[0] = v0.x; h[1] = v0.y; h[2] = v0.z; h[3] = v0.w;
        h[4] = v1.x; h[5] = v1.y; h[6] = v1.z; h[7] = v1.w;
    }

    float Aneg[8];
    {
        const float* Arow = Ap + (hh * D_DIM + d) * N_DIM + n0;
#pragma unroll
        for (int j = 0; j < 2; ++j) {
            float4 a4 = *(const float4*)(Arow + j * 4);
            Aneg[4*j+0] = NLOG2E * a4.x; Aneg[4*j+1] = NLOG2E * a4.y;
            Aneg[4*j+2] = NLOG2E * a4.z; Aneg[4*j+3] = NLOG2E * a4.w;
        }
    }

    const float Dv = Dp[hh];

    __syncthreads();

#pragma unroll
    for (int st = 0; st < 2; ++st) {
        float dtv[16], uv[16];
#pragma unroll
        for (int t2 = 0; t2 < 16; ++t2) {
            const int s = s0 + st * 16 + t2;
            dtv[t2] = dtp[base_ud + s * 512];
            uv[t2]  = up [base_ud + s * 512];
        }
#pragma unroll 4
        for (int t2 = 0; t2 < 16; ++t2) {
            const int tt = st * 16 + t2;
            const float kk = dtv[t2] * uv[t2];
            float y0 = 0.0f, y1 = 0.0f, y2 = 0.0f, y3 = 0.0f;
#pragma unroll
            for (int j = 0; j < 2; ++j) {
                const float4 Bv = *(const float4*)&lB[tt * 32 + n0 + j * 4];
                const float4 Cv = *(const float4*)&lC[tt * 32 + n0 + j * 4];
#pragma unroll
                for (int q = 0; q < 4; ++q) {
                    const int jn = j * 4 + q;
                    const float bq = (q == 0) ? Bv.x : (q == 1) ? Bv.y : (q == 2) ? Bv.z : Bv.w;
                    const float cq = (q == 0) ? Cv.x : (q == 1) ? Cv.y : (q == 2) ? Cv.z : Cv.w;
                    const float e = __builtin_amdgcn_exp2f(dtv[t2] * Aneg[jn]);
                    h[jn] = fmaf(e, h[jn], kk * bq);
                    if (q == 0)      y0 = fmaf(h[jn], cq, y0);
                    else if (q == 1) y1 = fmaf(h[jn], cq, y1);
                    else if (q == 2) y2 = fmaf(h[jn], cq, y2);
                    else             y3 = fmaf(h[jn], cq, y3);
                }
            }
            float y = (y0 + y1) + (y2 + y3);
            y += __shfl_xor(y, 16);
            y += __shfl_xor(y, 32);
            if (nq == 0) outp[base_ud + (s0 + tt) * 512] = fmaf(Dv, uv[t2], y);
        }
    }
}

} // namespace

extern "C" void kernel_launch(void* const* d_in, const int* in_sizes, int n_in,
                              void* d_out, int out_size, void* d_ws, size_t ws_size,
                              hipStream_t stream)
{
    const float* u  = (const float*)d_in[0];
    const float* dt = (const float*)d_in[1];
    const float* A  = (const float*)d_in[2];
    const float* B  = (const float*)d_in[3];
    const float* C  = (const float*)d_in[4];
    const float* D  = (const float*)d_in[5];
    float* out = (float*)d_out;

    float* sdtb = (float*)d_ws;                         // 0.25 MB
    float* bagg = sdtb + (size_t)NKC * 1024;            // 8.4 MB
    float* pref = bagg + (size_t)NKC * 32 * 1024;       // 8.4 MB

    ssm_k1<<<dim3(16 * NKC), dim3(256), 0, stream>>>(dt, u, A, B, sdtb, bagg);
    ssm_k2<<<dim3(512),      dim3(256), 0, stream>>>(sdtb, bagg, A, pref);
    ssm_k3<<<dim3(16 * NKC), dim3(256), 0, stream>>>(dt, u, A, B, C, D, pref, out);
}

// Round 19
// 42.435 us; speedup vs baseline: 5.1842x; 1.0384x over previous
//
#include <hip/hip_runtime.h>

namespace {

constexpr int S_LEN = 2048;
constexpr int H_N   = 8;
constexpr int D_DIM = 64;
constexpr int N_DIM = 32;
constexpr int TW    = 32;             // timesteps per chunk
constexpr int NKC   = S_LEN / TW;     // 64 chunks per (b,h)
constexpr int SEGL  = NKC / 4;        // 16 chunks per K2 segment
constexpr float NLOG2E = -1.4426950408889634f;

// ws (all float):
//   sdtb: [kc][ch]      64*1024    (0.25 MB) — sum of dt over chunk
//   bagg: [kc][ch][n]   64*1024*32 (8.4 MB)  — chunk b-aggregate (n contiguous)
//   pref: [kc][ch][n]   64*1024*32 (8.4 MB)  — state entering chunk
// K1/K3: block = bh*64 + kc (256 thr = 4 waves, ONE chunk per block).
//   wave w = d-quarter: d = w*16 + (lane&15); nq = lane>>4; n0 = nq*8.
//   ALL inputs (dt, u, B, C) staged cooperatively into LDS once per block
//   (2 float4 per thread per array) + one barrier; the t-loop is pure
//   LDS + ALU (R18 still issued ~70 VMEM insts/thread for dt/u with 4x
//   nq-duplication and two load walls — this removes them).
// K2: thread = (ch, n, seg); 4 segments of 16 chunks, register scan +
//   4-lane shuffle composition (2048 waves).

__global__ __launch_bounds__(256) void ssm_k1(
    const float* __restrict__ dtp, const float* __restrict__ up,
    const float* __restrict__ Ap,  const float* __restrict__ Bp,
    float* __restrict__ sdtb, float* __restrict__ bagg)
{
    __shared__ float ldt[TW * 64];        // 8 KB [t][d]
    __shared__ float lu [TW * 64];        // 8 KB
    __shared__ float lB [TW * 32];        // 4 KB [t][n]

    const int tid  = threadIdx.x;
    const int w    = tid >> 6;
    const int lane = tid & 63;
    const int dl   = lane & 15;
    const int nq   = lane >> 4;
    const int bh   = blockIdx.x >> 6;
    const int kc   = blockIdx.x & 63;
    const int b = bh >> 3, hh = bh & 7;
    const int d  = w * 16 + dl;
    const int n0 = nq * 8;
    const int ch = bh * 64 + d;
    const int s0 = kc * TW;

    const int base_ud = b * (S_LEN * 512) + hh * 64;          // + d later
    const int bB      = b * (S_LEN * 256) + hh * 32 + s0 * 256;

    // ---- cooperative stage: dt/u (512 f4 each, 2/thread), B (256 f4, 1/thread) ----
    {
        const int rB = tid >> 3, cB = tid & 7;
        *(float4*)&lB[rB * 32 + cB * 4] =
            *(const float4*)(Bp + bB + rB * 256 + cB * 4);
#pragma unroll
        for (int it = 0; it < 2; ++it) {
            const int idx = it * 256 + tid;       // 0..511
            const int r = idx >> 4, c = idx & 15;
            const int g = base_ud + (s0 + r) * 512 + c * 4;
            *(float4*)&ldt[r * 64 + c * 4] = *(const float4*)(dtp + g);
            *(float4*)&lu [r * 64 + c * 4] = *(const float4*)(up  + g);
        }
    }

    float Aneg[8];
    {
        const float* Arow = Ap + (hh * D_DIM + d) * N_DIM + n0;
#pragma unroll
        for (int j = 0; j < 2; ++j) {
            float4 a4 = *(const float4*)(Arow + j * 4);
            Aneg[4*j+0] = NLOG2E * a4.x; Aneg[4*j+1] = NLOG2E * a4.y;
            Aneg[4*j+2] = NLOG2E * a4.z; Aneg[4*j+3] = NLOG2E * a4.w;
        }
    }

    __syncthreads();

    float bA[8] = {0,0,0,0,0,0,0,0};
    float sdt = 0.0f;

#pragma unroll 4
    for (int tt = 0; tt < TW; ++tt) {
        const float dtv = ldt[tt * 64 + d];
        const float uv  = lu [tt * 64 + d];
        const float kk  = dtv * uv;
        sdt += dtv;
#pragma unroll
        for (int j = 0; j < 2; ++j) {
            const float4 Bv = *(const float4*)&lB[tt * 32 + n0 + j * 4];
#pragma unroll
            for (int q = 0; q < 4; ++q) {
                const int jn = j * 4 + q;
                const float bq = (q == 0) ? Bv.x : (q == 1) ? Bv.y : (q == 2) ? Bv.z : Bv.w;
                const float e = __builtin_amdgcn_exp2f(dtv * Aneg[jn]);
                bA[jn] = fmaf(e, bA[jn], kk * bq);
            }
        }
    }

    if (nq == 0) sdtb[kc * 1024 + ch] = sdt;
    {
        float* dst = bagg + (size_t)kc * 32768 + ch * 32 + n0;
        *(float4*)(dst + 0) = make_float4(bA[0], bA[1], bA[2], bA[3]);
        *(float4*)(dst + 4) = make_float4(bA[4], bA[5], bA[6], bA[7]);
    }
}

__global__ __launch_bounds__(256) void ssm_k2(
    const float* __restrict__ sdtb, const float* __restrict__ bagg,
    const float* __restrict__ Ap,   float* __restrict__ pref)
{
    const int T   = blockIdx.x * 256 + threadIdx.x;   // 131072 threads = (ch, n, seg)
    const int seg = T & 3;
    const int n   = (T >> 2) & 31;
    const int ch  = T >> 7;
    const int d   = ch & 63;
    const int hh  = (ch >> 6) & 7;
    const float Aneg1 = NLOG2E * Ap[(hh * D_DIM + d) * N_DIM + n];

    const int k0 = seg * SEGL;
    const size_t base = (size_t)ch * 32 + n;

    float bb[SEGL], av[SEGL];
#pragma unroll
    for (int i = 0; i < SEGL; ++i) {
        bb[i] = bagg[(size_t)(k0 + i) * 32768 + base];
        av[i] = sdtb[(k0 + i) * 1024 + ch];
    }
#pragma unroll
    for (int i = 0; i < SEGL; ++i)
        av[i] = __builtin_amdgcn_exp2f(Aneg1 * av[i]);

    float bseg = 0.0f, Aseg = 1.0f;
#pragma unroll
    for (int i = 0; i < SEGL; ++i) {
        bseg = fmaf(av[i], bseg, bb[i]);
        Aseg *= av[i];
    }

    {
        float Au = __shfl_up(Aseg, 1, 4), bu = __shfl_up(bseg, 1, 4);
        if (seg >= 1) { bseg = fmaf(Aseg, bu, bseg); Aseg *= Au; }
        Au = __shfl_up(Aseg, 2, 4); bu = __shfl_up(bseg, 2, 4);
        if (seg >= 2) { bseg = fmaf(Aseg, bu, bseg); Aseg *= Au; }
    }
    const float ebu = __shfl_up(bseg, 1, 4);
    float p = (seg == 0) ? 0.0f : ebu;

#pragma unroll
    for (int i = 0; i < SEGL; ++i) {
        pref[(size_t)(k0 + i) * 32768 + base] = p;
        p = fmaf(av[i], p, bb[i]);
    }
}

__global__ __launch_bounds__(256) void ssm_k3(
    const float* __restrict__ dtp, const float* __restrict__ up,
    const float* __restrict__ Ap,  const float* __restrict__ Bp,
    const float* __restrict__ Cp,  const float* __restrict__ Dp,
    const float* __restrict__ pref, float* __restrict__ outp)
{
    __shared__ float ldt[TW * 64];        // 8 KB
    __shared__ float lu [TW * 64];        // 8 KB
    __shared__ float lB [TW * 32];        // 4 KB
    __shared__ float lC [TW * 32];        // 4 KB

    const int tid  = threadIdx.x;
    const int w    = tid >> 6;
    const int lane = tid & 63;
    const int dl   = lane & 15;
    const int nq   = lane >> 4;
    const int bh   = blockIdx.x >> 6;
    const int kc   = blockIdx.x & 63;
    const int b = bh >> 3, hh = bh & 7;
    const int d  = w * 16 + dl;
    const int n0 = nq * 8;
    const int ch = bh * 64 + d;
    const int s0 = kc * TW;

    const int base_ud = b * (S_LEN * 512) + hh * 64;
    const int bB      = b * (S_LEN * 256) + hh * 32 + s0 * 256;

    // ---- cooperative stage: dt/u/B/C ----
    {
        const int rB = tid >> 3, cB = tid & 7;
        *(float4*)&lB[rB * 32 + cB * 4] =
            *(const float4*)(Bp + bB + rB * 256 + cB * 4);
        *(float4*)&lC[rB * 32 + cB * 4] =
            *(const float4*)(Cp + bB + rB * 256 + cB * 4);
#pragma unroll
        for (int it = 0; it < 2; ++it) {
            const int idx = it * 256 + tid;
            const int r = idx >> 4, c = idx & 15;
            const int g = base_ud + (s0 + r) * 512 + c * 4;
            *(float4*)&ldt[r * 64 + c * 4] = *(const float4*)(dtp + g);
            *(float4*)&lu [r * 64 + c * 4] = *(const float4*)(up  + g);
        }
    }

    // ---- entering state: 2 contiguous float4 loads ----
    float h[8];
    {
        const float* ps = pref + (size_t)kc * 32768 + ch * 32 + n0;
        float4 v0 = *(const float4*)(ps + 0);
        float4 v1 = *(const float4*)(ps + 4);
        h[0] = v0.x; h[1] = v0.y; h[2] = v0.z; h[3] = v0.w;
        h[4] = v1.x; h[5] = v1.y; h[6] = v1.z; h[7] = v1.w;
    }

    float Aneg[8];
    {
        const float* Arow = Ap + (hh * D_DIM + d) * N_DIM + n0;
#pragma unroll
        for (int j = 0; j < 2; ++j) {
            float4 a4 = *(const float4*)(Arow + j * 4);
            Aneg[4*j+0] = NLOG2E * a4.x; Aneg[4*j+1] = NLOG2E * a4.y;
            Aneg[4*j+2] = NLOG2E * a4.z; Aneg[4*j+3] = NLOG2E * a4.w;
        }
    }

    const float Dv = Dp[hh];

    __syncthreads();

#pragma unroll 4
    for (int tt = 0; tt < TW; ++tt) {
        const float dtv = ldt[tt * 64 + d];
        const float uv  = lu [tt * 64 + d];
        const float kk  = dtv * uv;
        float y0 = 0.0f, y1 = 0.0f, y2 = 0.0f, y3 = 0.0f;
#pragma unroll
        for (int j = 0; j < 2; ++j) {
            const float4 Bv = *(const float4*)&lB[tt * 32 + n0 + j * 4];
            const float4 Cv = *(const float4*)&lC[tt * 32 + n0 + j * 4];
#pragma unroll
            for (int q = 0; q < 4; ++q) {
                const int jn = j * 4 + q;
                const float bq = (q == 0) ? Bv.x : (q == 1) ? Bv.y : (q == 2) ? Bv.z : Bv.w;
                const float cq = (q == 0) ? Cv.x : (q == 1) ? Cv.y : (q == 2) ? Cv.z : Cv.w;
                const float e = __builtin_amdgcn_exp2f(dtv * Aneg[jn]);
                h[jn] = fmaf(e, h[jn], kk * bq);
                if (q == 0)      y0 = fmaf(h[jn], cq, y0);
                else if (q == 1) y1 = fmaf(h[jn], cq, y1);
                else if (q == 2) y2 = fmaf(h[jn], cq, y2);
                else             y3 = fmaf(h[jn], cq, y3);
            }
        }
        float y = (y0 + y1) + (y2 + y3);
        y += __shfl_xor(y, 16);
        y += __shfl_xor(y, 32);
        if (nq == 0) outp[base_ud + d + (s0 + tt) * 512] = fmaf(Dv, uv, y);
    }
}

} // namespace

extern "C" void kernel_launch(void* const* d_in, const int* in_sizes, int n_in,
                              void* d_out, int out_size, void* d_ws, size_t ws_size,
                              hipStream_t stream)
{
    const float* u  = (const float*)d_in[0];
    const float* dt = (const float*)d_in[1];
    const float* A  = (const float*)d_in[2];
    const float* B  = (const float*)d_in[3];
    const float* C  = (const float*)d_in[4];
    const float* D  = (const float*)d_in[5];
    float* out = (float*)d_out;

    float* sdtb = (float*)d_ws;                         // 0.25 MB
    float* bagg = sdtb + (size_t)NKC * 1024;            // 8.4 MB
    float* pref = bagg + (size_t)NKC * 32 * 1024;       // 8.4 MB

    ssm_k1<<<dim3(16 * NKC), dim3(256), 0, stream>>>(dt, u, A, B, sdtb, bagg);
    ssm_k2<<<dim3(512),      dim3(256), 0, stream>>>(sdtb, bagg, A, pref);
    ssm_k3<<<dim3(16 * NKC), dim3(256), 0, stream>>>(dt, u, A, B, C, D, pref, out);
}

// Round 21
// 41.713 us; speedup vs baseline: 5.2739x; 1.0173x over previous
//
#include <hip/hip_runtime.h>

namespace {

typedef float v2f __attribute__((ext_vector_type(2)));

__device__ __forceinline__ v2f vfma(v2f a, v2f b, v2f c) {
#if __has_builtin(__builtin_elementwise_fma)
    return __builtin_elementwise_fma(a, b, c);
#else
    v2f r; r.x = fmaf(a.x, b.x, c.x); r.y = fmaf(a.y, b.y, c.y); return r;
#endif
}

constexpr int S_LEN = 2048;
constexpr int H_N   = 8;
constexpr int D_DIM = 64;
constexpr int N_DIM = 32;
constexpr int TW    = 32;             // timesteps per chunk
constexpr int NKC   = S_LEN / TW;     // 64 chunks per (b,h)
constexpr int SEGL  = NKC / 4;        // 16 chunks per K2 segment
constexpr float NLOG2E = -1.4426950408889634f;

// ws (all float):
//   sdtb: [kc][ch]      64*1024    (0.25 MB) — sum of dt over chunk
//   bagg: [kc][ch][n]   64*1024*32 (8.4 MB)  — chunk b-aggregate (n contiguous)
//   pref: [kc][ch][n]   64*1024*32 (8.4 MB)  — state entering chunk
// K1/K3: R19 structure (full cooperative LDS staging of dt/u/B/C, one
//   barrier, 256 thr = 4 waves = ONE chunk; wave w: d = w*16+(lane&15),
//   nq = lane>>4, n0 = nq*8). Inner math on <2 x float> vectors so the
//   backend can emit v_pk_mul_f32 / v_pk_fma_f32 (R20's inline-asm pk
//   attempt mis-set VOP3P modifiers and broke hi-half results — use
//   compiler codegen, never hand-rolled VOP3P).
// K2: thread = (ch, n, seg); 4 segments of 16, shuffle composition.

__global__ __launch_bounds__(256) void ssm_k1(
    const float* __restrict__ dtp, const float* __restrict__ up,
    const float* __restrict__ Ap,  const float* __restrict__ Bp,
    float* __restrict__ sdtb, float* __restrict__ bagg)
{
    __shared__ float ldt[TW * 64];        // 8 KB [t][d]
    __shared__ float lu [TW * 64];        // 8 KB
    __shared__ float lB [TW * 32];        // 4 KB [t][n]

    const int tid  = threadIdx.x;
    const int w    = tid >> 6;
    const int lane = tid & 63;
    const int dl   = lane & 15;
    const int nq   = lane >> 4;
    const int bh   = blockIdx.x >> 6;
    const int kc   = blockIdx.x & 63;
    const int b = bh >> 3, hh = bh & 7;
    const int d  = w * 16 + dl;
    const int n0 = nq * 8;
    const int ch = bh * 64 + d;
    const int s0 = kc * TW;

    const int base_ud = b * (S_LEN * 512) + hh * 64;
    const int bB      = b * (S_LEN * 256) + hh * 32 + s0 * 256;

    // ---- cooperative stage ----
    {
        const int rB = tid >> 3, cB = tid & 7;
        *(float4*)&lB[rB * 32 + cB * 4] =
            *(const float4*)(Bp + bB + rB * 256 + cB * 4);
#pragma unroll
        for (int it = 0; it < 2; ++it) {
            const int idx = it * 256 + tid;
            const int r = idx >> 4, c = idx & 15;
            const int g = base_ud + (s0 + r) * 512 + c * 4;
            *(float4*)&ldt[r * 64 + c * 4] = *(const float4*)(dtp + g);
            *(float4*)&lu [r * 64 + c * 4] = *(const float4*)(up  + g);
        }
    }

    v2f Aneg2[4];
    {
        const float* Arow = Ap + (hh * D_DIM + d) * N_DIM + n0;
#pragma unroll
        for (int j = 0; j < 4; ++j) {
            v2f a2 = *(const v2f*)(Arow + 2 * j);
            Aneg2[j] = a2 * NLOG2E;
        }
    }

    __syncthreads();

    v2f bA2[4];
#pragma unroll
    for (int j = 0; j < 4; ++j) bA2[j] = (v2f)(0.0f);
    float sdt = 0.0f;

#pragma unroll 4
    for (int tt = 0; tt < TW; ++tt) {
        const float dtv = ldt[tt * 64 + d];
        const float uv  = lu [tt * 64 + d];
        const float kk  = dtv * uv;
        sdt += dtv;
        const v2f dt2 = (v2f)(dtv);
        const v2f kk2 = (v2f)(kk);
#pragma unroll
        for (int j = 0; j < 4; ++j) {
            const v2f B2 = *(const v2f*)&lB[tt * 32 + n0 + 2 * j];
            const v2f arg = dt2 * Aneg2[j];
            v2f e;
            e.x = __builtin_amdgcn_exp2f(arg.x);
            e.y = __builtin_amdgcn_exp2f(arg.y);
            bA2[j] = vfma(e, bA2[j], kk2 * B2);
        }
    }

    if (nq == 0) sdtb[kc * 1024 + ch] = sdt;
    {
        float* dst = bagg + (size_t)kc * 32768 + ch * 32 + n0;
        *(float4*)(dst + 0) = make_float4(bA2[0].x, bA2[0].y, bA2[1].x, bA2[1].y);
        *(float4*)(dst + 4) = make_float4(bA2[2].x, bA2[2].y, bA2[3].x, bA2[3].y);
    }
}

__global__ __launch_bounds__(256) void ssm_k2(
    const float* __restrict__ sdtb, const float* __restrict__ bagg,
    const float* __restrict__ Ap,   float* __restrict__ pref)
{
    const int T   = blockIdx.x * 256 + threadIdx.x;   // 131072 threads = (ch, n, seg)
    const int seg = T & 3;
    const int n   = (T >> 2) & 31;
    const int ch  = T >> 7;
    const int d   = ch & 63;
    const int hh  = (ch >> 6) & 7;
    const float Aneg1 = NLOG2E * Ap[(hh * D_DIM + d) * N_DIM + n];

    const int k0 = seg * SEGL;
    const size_t base = (size_t)ch * 32 + n;

    float bb[SEGL], av[SEGL];
#pragma unroll
    for (int i = 0; i < SEGL; ++i) {
        bb[i] = bagg[(size_t)(k0 + i) * 32768 + base];
        av[i] = sdtb[(k0 + i) * 1024 + ch];
    }
#pragma unroll
    for (int i = 0; i < SEGL; ++i)
        av[i] = __builtin_amdgcn_exp2f(Aneg1 * av[i]);

    float bseg = 0.0f, Aseg = 1.0f;
#pragma unroll
    for (int i = 0; i < SEGL; ++i) {
        bseg = fmaf(av[i], bseg, bb[i]);
        Aseg *= av[i];
    }

    {
        float Au = __shfl_up(Aseg, 1, 4), bu = __shfl_up(bseg, 1, 4);
        if (seg >= 1) { bseg = fmaf(Aseg, bu, bseg); Aseg *= Au; }
        Au = __shfl_up(Aseg, 2, 4); bu = __shfl_up(bseg, 2, 4);
        if (seg >= 2) { bseg = fmaf(Aseg, bu, bseg); Aseg *= Au; }
    }
    const float ebu = __shfl_up(bseg, 1, 4);
    float p = (seg == 0) ? 0.0f : ebu;

#pragma unroll
    for (int i = 0; i < SEGL; ++i) {
        pref[(size_t)(k0 + i) * 32768 + base] = p;
        p = fmaf(av[i], p, bb[i]);
    }
}

__global__ __launch_bounds__(256) void ssm_k3(
    const float* __restrict__ dtp, const float* __restrict__ up,
    const float* __restrict__ Ap,  const float* __restrict__ Bp,
    const float* __restrict__ Cp,  const float* __restrict__ Dp,
    const float* __restrict__ pref, float* __restrict__ outp)
{
    __shared__ float ldt[TW * 64];        // 8 KB
    __shared__ float lu [TW * 64];        // 8 KB
    __shared__ float lB [TW * 32];        // 4 KB
    __shared__ float lC [TW * 32];        // 4 KB

    const int tid  = threadIdx.x;
    const int w    = tid >> 6;
    const int lane = tid & 63;
    const int dl   = lane & 15;
    const int nq   = lane >> 4;
    const int bh   = blockIdx.x >> 6;
    const int kc   = blockIdx.x & 63;
    const int b = bh >> 3, hh = bh & 7;
    const int d  = w * 16 + dl;
    const int n0 = nq * 8;
    const int ch = bh * 64 + d;
    const int s0 = kc * TW;

    const int base_ud = b * (S_LEN * 512) + hh * 64;
    const int bB      = b * (S_LEN * 256) + hh * 32 + s0 * 256;

    // ---- cooperative stage ----
    {
        const int rB = tid >> 3, cB = tid & 7;
        *(float4*)&lB[rB * 32 + cB * 4] =
            *(const float4*)(Bp + bB + rB * 256 + cB * 4);
        *(float4*)&lC[rB * 32 + cB * 4] =
            *(const float4*)(Cp + bB + rB * 256 + cB * 4);
#pragma unroll
        for (int it = 0; it < 2; ++it) {
            const int idx = it * 256 + tid;
            const int r = idx >> 4, c = idx & 15;
            const int g = base_ud + (s0 + r) * 512 + c * 4;
            *(float4*)&ldt[r * 64 + c * 4] = *(const float4*)(dtp + g);
            *(float4*)&lu [r * 64 + c * 4] = *(const float4*)(up  + g);
        }
    }

    // ---- entering state ----
    v2f h2[4];
    {
        const float* ps = pref + (size_t)kc * 32768 + ch * 32 + n0;
        float4 v0 = *(const float4*)(ps + 0);
        float4 v1 = *(const float4*)(ps + 4);
        h2[0].x = v0.x; h2[0].y = v0.y; h2[1].x = v0.z; h2[1].y = v0.w;
        h2[2].x = v1.x; h2[2].y = v1.y; h2[3].x = v1.z; h2[3].y = v1.w;
    }

    v2f Aneg2[4];
    {
        const float* Arow = Ap + (hh * D_DIM + d) * N_DIM + n0;
#pragma unroll
        for (int j = 0; j < 4; ++j) {
            v2f a2 = *(const v2f*)(Arow + 2 * j);
            Aneg2[j] = a2 * NLOG2E;
        }
    }

    const float Dv = Dp[hh];

    __syncthreads();

#pragma unroll 4
    for (int tt = 0; tt < TW; ++tt) {
        const float dtv = ldt[tt * 64 + d];
        const float uv  = lu [tt * 64 + d];
        const float kk  = dtv * uv;
        const v2f dt2 = (v2f)(dtv);
        const v2f kk2 = (v2f)(kk);
        v2f ya = (v2f)(0.0f);
        v2f yb = (v2f)(0.0f);
#pragma unroll
        for (int j = 0; j < 4; ++j) {
            const v2f B2 = *(const v2f*)&lB[tt * 32 + n0 + 2 * j];
            const v2f C2 = *(const v2f*)&lC[tt * 32 + n0 + 2 * j];
            const v2f arg = dt2 * Aneg2[j];
            v2f e;
            e.x = __builtin_amdgcn_exp2f(arg.x);
            e.y = __builtin_amdgcn_exp2f(arg.y);
            h2[j] = vfma(e, h2[j], kk2 * B2);
            if (j & 1) yb = vfma(h2[j], C2, yb);
            else       ya = vfma(h2[j], C2, ya);
        }
        float y = (ya.x + ya.y) + (yb.x + yb.y);
        y += __shfl_xor(y, 16);
        y += __shfl_xor(y, 32);
        if (nq == 0) outp[base_ud + d + (s0 + tt) * 512] = fmaf(Dv, uv, y);
    }
}

} // namespace

extern "C" void kernel_launch(void* const* d_in, const int* in_sizes, int n_in,
                              void* d_out, int out_size, void* d_ws, size_t ws_size,
                              hipStream_t stream)
{
    const float* u  = (const float*)d_in[0];
    const float* dt = (const float*)d_in[1];
    const float* A  = (const float*)d_in[2];
    const float* B  = (const float*)d_in[3];
    const float* C  = (const float*)d_in[4];
    const float* D  = (const float*)d_in[5];
    float* out = (float*)d_out;

    float* sdtb = (float*)d_ws;                         // 0.25 MB
    float* bagg = sdtb + (size_t)NKC * 1024;            // 8.4 MB
    float* pref = bagg + (size_t)NKC * 32 * 1024;       // 8.4 MB

    ssm_k1<<<dim3(16 * NKC), dim3(256), 0, stream>>>(dt, u, A, B, sdtb, bagg);
    ssm_k2<<<dim3(512),      dim3(256), 0, stream>>>(sdtb, bagg, A, pref);
    ssm_k3<<<dim3(16 * NKC), dim3(256), 0, stream>>>(dt, u, A, B, C, D, pref, out);
}

// Round 22
// 41.495 us; speedup vs baseline: 5.3016x; 1.0053x over previous
//
#include <hip/hip_runtime.h>

namespace {

typedef float v2f __attribute__((ext_vector_type(2)));

__device__ __forceinline__ v2f vfma(v2f a, v2f b, v2f c) {
#if __has_builtin(__builtin_elementwise_fma)
    return __builtin_elementwise_fma(a, b, c);
#else
    v2f r; r.x = fmaf(a.x, b.x, c.x); r.y = fmaf(a.y, b.y, c.y); return r;
#endif
}

constexpr int S_LEN = 2048;
constexpr int H_N   = 8;
constexpr int D_DIM = 64;
constexpr int N_DIM = 32;
constexpr int TW    = 32;             // timesteps per chunk
constexpr int HALF  = 16;             // double-buffer half
constexpr int NKC   = S_LEN / TW;     // 64 chunks per (b,h)
constexpr int SEGL  = NKC / 4;        // 16 chunks per K2 segment
constexpr float NLOG2E = -1.4426950408889634f;

// ws (all float):
//   sdtb: [kc][ch]      64*1024    (0.25 MB)
//   bagg: [kc][ch][n]   64*1024*32 (8.4 MB)
//   pref: [kc][ch][n]   64*1024*32 (8.4 MB)
// K1/K3: R21 structure (256 thr = 4 waves = ONE chunk; wave w:
//   d = w*16+(lane&15), nq = lane>>4, n0 = nq*8; packed-fp32 inner math).
//   NEW (T14 async-stage): chunk split into two 16-step halves with disjoint
//   LDS buffers. half-1 global loads are ISSUED before compute(half-0), so
//   HBM latency/transfer overlaps VALU work — the grid is exactly one
//   residency round (1024 blocks = 4/CU), so without this, all blocks
//   stage in lockstep (VALU idle) then compute (memory idle), serially.
// K2: thread = (ch, n, seg); 4 segments of 16, shuffle composition.

__global__ __launch_bounds__(256) void ssm_k1(
    const float* __restrict__ dtp, const float* __restrict__ up,
    const float* __restrict__ Ap,  const float* __restrict__ Bp,
    float* __restrict__ sdtb, float* __restrict__ bagg)
{
    __shared__ float ldt[2][HALF * 64];   // 2 x 4 KB
    __shared__ float lu [2][HALF * 64];   // 2 x 4 KB
    __shared__ float lB [2][HALF * 32];   // 2 x 2 KB

    const int tid  = threadIdx.x;
    const int w    = tid >> 6;
    const int lane = tid & 63;
    const int dl   = lane & 15;
    const int nq   = lane >> 4;
    const int bh   = blockIdx.x >> 6;
    const int kc   = blockIdx.x & 63;
    const int b = bh >> 3, hh = bh & 7;
    const int d  = w * 16 + dl;
    const int n0 = nq * 8;
    const int ch = bh * 64 + d;
    const int s0 = kc * TW;

    const int base_ud = b * (S_LEN * 512) + hh * 64;
    const int bB      = b * (S_LEN * 256) + hh * 32 + s0 * 256;

    const int rT = tid >> 4, cT = tid & 15;       // dt/u: 256 f4 per half
    const int rB8 = tid >> 3, cB8 = tid & 7;      // B: 128 f4 per half (tid<128)

    // ---- load half-0 into registers ----
    float4 rdt = *(const float4*)(dtp + base_ud + (s0 + rT) * 512 + cT * 4);
    float4 ru  = *(const float4*)(up  + base_ud + (s0 + rT) * 512 + cT * 4);
    float4 rb;
    if (tid < 128) rb = *(const float4*)(Bp + bB + rB8 * 256 + cB8 * 4);

    v2f Aneg2[4];
    {
        const float* Arow = Ap + (hh * D_DIM + d) * N_DIM + n0;
#pragma unroll
        for (int j = 0; j < 4; ++j) {
            v2f a2 = *(const v2f*)(Arow + 2 * j);
            Aneg2[j] = a2 * NLOG2E;
        }
    }

    // ---- write half-0 to LDS ----
    *(float4*)&ldt[0][rT * 64 + cT * 4] = rdt;
    *(float4*)&lu [0][rT * 64 + cT * 4] = ru;
    if (tid < 128) *(float4*)&lB[0][rB8 * 32 + cB8 * 4] = rb;
    __syncthreads();

    // ---- issue half-1 global loads (latency hides under compute half-0) ----
    rdt = *(const float4*)(dtp + base_ud + (s0 + HALF + rT) * 512 + cT * 4);
    ru  = *(const float4*)(up  + base_ud + (s0 + HALF + rT) * 512 + cT * 4);
    if (tid < 128) rb = *(const float4*)(Bp + bB + HALF * 256 + rB8 * 256 + cB8 * 4);

    v2f bA2[4];
#pragma unroll
    for (int j = 0; j < 4; ++j) bA2[j] = (v2f)(0.0f);
    float sdt = 0.0f;

    auto compute_half = [&](int hf) {
#pragma unroll 4
        for (int t2 = 0; t2 < HALF; ++t2) {
            const float dtv = ldt[hf][t2 * 64 + d];
            const float uv  = lu [hf][t2 * 64 + d];
            const float kk  = dtv * uv;
            sdt += dtv;
            const v2f dt2 = (v2f)(dtv);
            const v2f kk2 = (v2f)(kk);
#pragma unroll
            for (int j = 0; j < 4; ++j) {
                const v2f B2 = *(const v2f*)&lB[hf][t2 * 32 + n0 + 2 * j];
                const v2f arg = dt2 * Aneg2[j];
                v2f e;
                e.x = __builtin_amdgcn_exp2f(arg.x);
                e.y = __builtin_amdgcn_exp2f(arg.y);
                bA2[j] = vfma(e, bA2[j], kk2 * B2);
            }
        }
    };

    compute_half(0);

    // ---- write half-1, sync, compute ----
    *(float4*)&ldt[1][rT * 64 + cT * 4] = rdt;
    *(float4*)&lu [1][rT * 64 + cT * 4] = ru;
    if (tid < 128) *(float4*)&lB[1][rB8 * 32 + cB8 * 4] = rb;
    __syncthreads();

    compute_half(1);

    if (nq == 0) sdtb[kc * 1024 + ch] = sdt;
    {
        float* dst = bagg + (size_t)kc * 32768 + ch * 32 + n0;
        *(float4*)(dst + 0) = make_float4(bA2[0].x, bA2[0].y, bA2[1].x, bA2[1].y);
        *(float4*)(dst + 4) = make_float4(bA2[2].x, bA2[2].y, bA2[3].x, bA2[3].y);
    }
}

__global__ __launch_bounds__(256) void ssm_k2(
    const float* __restrict__ sdtb, const float* __restrict__ bagg,
    const float* __restrict__ Ap,   float* __restrict__ pref)
{
    const int T   = blockIdx.x * 256 + threadIdx.x;   // 131072 threads = (ch, n, seg)
    const int seg = T & 3;
    const int n   = (T >> 2) & 31;
    const int ch  = T >> 7;
    const int d   = ch & 63;
    const int hh  = (ch >> 6) & 7;
    const float Aneg1 = NLOG2E * Ap[(hh * D_DIM + d) * N_DIM + n];

    const int k0 = seg * SEGL;
    const size_t base = (size_t)ch * 32 + n;

    float bb[SEGL], av[SEGL];
#pragma unroll
    for (int i = 0; i < SEGL; ++i) {
        bb[i] = bagg[(size_t)(k0 + i) * 32768 + base];
        av[i] = sdtb[(k0 + i) * 1024 + ch];
    }
#pragma unroll
    for (int i = 0; i < SEGL; ++i)
        av[i] = __builtin_amdgcn_exp2f(Aneg1 * av[i]);

    float bseg = 0.0f, Aseg = 1.0f;
#pragma unroll
    for (int i = 0; i < SEGL; ++i) {
        bseg = fmaf(av[i], bseg, bb[i]);
        Aseg *= av[i];
    }

    {
        float Au = __shfl_up(Aseg, 1, 4), bu = __shfl_up(bseg, 1, 4);
        if (seg >= 1) { bseg = fmaf(Aseg, bu, bseg); Aseg *= Au; }
        Au = __shfl_up(Aseg, 2, 4); bu = __shfl_up(bseg, 2, 4);
        if (seg >= 2) { bseg = fmaf(Aseg, bu, bseg); Aseg *= Au; }
    }
    const float ebu = __shfl_up(bseg, 1, 4);
    float p = (seg == 0) ? 0.0f : ebu;

#pragma unroll
    for (int i = 0; i < SEGL; ++i) {
        pref[(size_t)(k0 + i) * 32768 + base] = p;
        p = fmaf(av[i], p, bb[i]);
    }
}

__global__ __launch_bounds__(256) void ssm_k3(
    const float* __restrict__ dtp, const float* __restrict__ up,
    const float* __restrict__ Ap,  const float* __restrict__ Bp,
    const float* __restrict__ Cp,  const float* __restrict__ Dp,
    const float* __restrict__ pref, float* __restrict__ outp)
{
    __shared__ float ldt[2][HALF * 64];   // 2 x 4 KB
    __shared__ float lu [2][HALF * 64];   // 2 x 4 KB
    __shared__ float lB [2][HALF * 32];   // 2 x 2 KB
    __shared__ float lC [2][HALF * 32];   // 2 x 2 KB

    const int tid  = threadIdx.x;
    const int w    = tid >> 6;
    const int lane = tid & 63;
    const int dl   = lane & 15;
    const int nq   = lane >> 4;
    const int bh   = blockIdx.x >> 6;
    const int kc   = blockIdx.x & 63;
    const int b = bh >> 3, hh = bh & 7;
    const int d  = w * 16 + dl;
    const int n0 = nq * 8;
    const int ch = bh * 64 + d;
    const int s0 = kc * TW;

    const int base_ud = b * (S_LEN * 512) + hh * 64;
    const int bB      = b * (S_LEN * 256) + hh * 32 + s0 * 256;

    const int rT = tid >> 4, cT = tid & 15;
    const int t8 = tid & 127;
    const int rB8 = t8 >> 3, cB8 = t8 & 7;    // tid<128 -> B, tid>=128 -> C

    // ---- load half-0 into registers ----
    float4 rdt = *(const float4*)(dtp + base_ud + (s0 + rT) * 512 + cT * 4);
    float4 ru  = *(const float4*)(up  + base_ud + (s0 + rT) * 512 + cT * 4);
    float4 rbc;
    if (tid < 128) rbc = *(const float4*)(Bp + bB + rB8 * 256 + cB8 * 4);
    else           rbc = *(const float4*)(Cp + bB + rB8 * 256 + cB8 * 4);

    // ---- entering state + Aneg (independent loads, overlap staging) ----
    v2f h2[4];
    {
        const float* ps = pref + (size_t)kc * 32768 + ch * 32 + n0;
        float4 v0 = *(const float4*)(ps + 0);
        float4 v1 = *(const float4*)(ps + 4);
        h2[0].x = v0.x; h2[0].y = v0.y; h2[1].x = v0.z; h2[1].y = v0.w;
        h2[2].x = v1.x; h2[2].y = v1.y; h2[3].x = v1.z; h2[3].y = v1.w;
    }
    v2f Aneg2[4];
    {
        const float* Arow = Ap + (hh * D_DIM + d) * N_DIM + n0;
#pragma unroll
        for (int j = 0; j < 4; ++j) {
            v2f a2 = *(const v2f*)(Arow + 2 * j);
            Aneg2[j] = a2 * NLOG2E;
        }
    }
    const float Dv = Dp[hh];

    // ---- write half-0 to LDS ----
    *(float4*)&ldt[0][rT * 64 + cT * 4] = rdt;
    *(float4*)&lu [0][rT * 64 + cT * 4] = ru;
    if (tid < 128) *(float4*)&lB[0][rB8 * 32 + cB8 * 4] = rbc;
    else           *(float4*)&lC[0][rB8 * 32 + cB8 * 4] = rbc;
    __syncthreads();

    // ---- issue half-1 global loads (hide under compute half-0) ----
    rdt = *(const float4*)(dtp + base_ud + (s0 + HALF + rT) * 512 + cT * 4);
    ru  = *(const float4*)(up  + base_ud + (s0 + HALF + rT) * 512 + cT * 4);
    if (tid < 128) rbc = *(const float4*)(Bp + bB + HALF * 256 + rB8 * 256 + cB8 * 4);
    else           rbc = *(const float4*)(Cp + bB + HALF * 256 + rB8 * 256 + cB8 * 4);

    auto compute_half = [&](int hf) {
#pragma unroll 4
        for (int t2 = 0; t2 < HALF; ++t2) {
            const float dtv = ldt[hf][t2 * 64 + d];
            const float uv  = lu [hf][t2 * 64 + d];
            const float kk  = dtv * uv;
            const v2f dt2 = (v2f)(dtv);
            const v2f kk2 = (v2f)(kk);
            v2f ya = (v2f)(0.0f);
            v2f yb = (v2f)(0.0f);
#pragma unroll
            for (int j = 0; j < 4; ++j) {
                const v2f B2 = *(const v2f*)&lB[hf][t2 * 32 + n0 + 2 * j];
                const v2f C2 = *(const v2f*)&lC[hf][t2 * 32 + n0 + 2 * j];
                const v2f arg = dt2 * Aneg2[j];
                v2f e;
                e.x = __builtin_amdgcn_exp2f(arg.x);
                e.y = __builtin_amdgcn_exp2f(arg.y);
                h2[j] = vfma(e, h2[j], kk2 * B2);
                if (j & 1) yb = vfma(h2[j], C2, yb);
                else       ya = vfma(h2[j], C2, ya);
            }
            float y = (ya.x + ya.y) + (yb.x + yb.y);
            y += __shfl_xor(y, 16);
            y += __shfl_xor(y, 32);
            if (nq == 0)
                outp[base_ud + d + (s0 + hf * HALF + t2) * 512] = fmaf(Dv, uv, y);
        }
    };

    compute_half(0);

    // ---- write half-1, sync, compute ----
    *(float4*)&ldt[1][rT * 64 + cT * 4] = rdt;
    *(float4*)&lu [1][rT * 64 + cT * 4] = ru;
    if (tid < 128) *(float4*)&lB[1][rB8 * 32 + cB8 * 4] = rbc;
    else           *(float4*)&lC[1][rB8 * 32 + cB8 * 4] = rbc;
    __syncthreads();

    compute_half(1);
}

} // namespace

extern "C" void kernel_launch(void* const* d_in, const int* in_sizes, int n_in,
                              void* d_out, int out_size, void* d_ws, size_t ws_size,
                              hipStream_t stream)
{
    const float* u  = (const float*)d_in[0];
    const float* dt = (const float*)d_in[1];
    const float* A  = (const float*)d_in[2];
    const float* B  = (const float*)d_in[3];
    const float* C  = (const float*)d_in[4];
    const float* D  = (const float*)d_in[5];
    float* out = (float*)d_out;

    float* sdtb = (float*)d_ws;                         // 0.25 MB
    float* bagg = sdtb + (size_t)NKC * 1024;            // 8.4 MB
    float* pref = bagg + (size_t)NKC * 32 * 1024;       // 8.4 MB

    ssm_k1<<<dim3(16 * NKC), dim3(256), 0, stream>>>(dt, u, A, B, sdtb, bagg);
    ssm_k2<<<dim3(512),      dim3(256), 0, stream>>>(sdtb, bagg, A, pref);
    ssm_k3<<<dim3(16 * NKC), dim3(256), 0, stream>>>(dt, u, A, B, C, D, pref, out);
}

// Round 23
// 41.074 us; speedup vs baseline: 5.3560x; 1.0103x over previous
//
#include <hip/hip_runtime.h>

namespace {

typedef float v2f __attribute__((ext_vector_type(2)));

__device__ __forceinline__ v2f vfma(v2f a, v2f b, v2f c) {
#if __has_builtin(__builtin_elementwise_fma)
    return __builtin_elementwise_fma(a, b, c);
#else
    v2f r; r.x = fmaf(a.x, b.x, c.x); r.y = fmaf(a.y, b.y, c.y); return r;
#endif
}

constexpr int S_LEN = 2048;
constexpr int H_N   = 8;
constexpr int D_DIM = 64;
constexpr int N_DIM = 32;
constexpr int TW    = 32;             // timesteps per chunk
constexpr int NKC   = S_LEN / TW;     // 64 chunks per (b,h)
constexpr int SEGL  = NKC / 4;        // 16 chunks per K2 segment
constexpr float NLOG2E = -1.4426950408889634f;

// ws (all float):
//   sdtb: [kc][ch]      64*1024    (0.25 MB)
//   bagg: [kc][ch][n]   64*1024*32 (8.4 MB)
//   pref: [kc][ch][n]   64*1024*32 (8.4 MB)
// K1/K3: R21 structure — 256 thr = 4 waves = ONE chunk; wave w:
//   d = w*16+(lane&15), nq = lane>>4, n0 = nq*8; full cooperative LDS
//   staging of dt/u/B/C (one barrier); packed-fp32 <2 x float> inner math.
// K2 FIX: thread index remapped to (seg, ch, n) with seg as the SLOW index —
//   previous (ch,n,seg) put 4 different 512KB-apart segments in adjacent
//   lanes, fragmenting every wave access into 4x64B; now each wave touches
//   64 consecutive floats (256 B) for all 32 r/w streams.
// K2: 4 segments of 16 chunks, register scan + cross-lane composition via
//   __shfl (seg stride is now 32768 threads -> use shfl on (lane) groups is
//   impossible; use a tiny LDS-free 2-round global approach instead: the
//   4 segment transforms per (ch,n) are combined via a second tiny pass).
//   -> Simpler: keep 4-lane shuffle composition but gather the 4 segs into
//   one lane-quad via __shfl with remapped lane math (see code).

__global__ __launch_bounds__(256) void ssm_k1(
    const float* __restrict__ dtp, const float* __restrict__ up,
    const float* __restrict__ Ap,  const float* __restrict__ Bp,
    float* __restrict__ sdtb, float* __restrict__ bagg)
{
    __shared__ float ldt[TW * 64];        // 8 KB [t][d]
    __shared__ float lu [TW * 64];        // 8 KB
    __shared__ float lB [TW * 32];        // 4 KB [t][n]

    const int tid  = threadIdx.x;
    const int w    = tid >> 6;
    const int lane = tid & 63;
    const int dl   = lane & 15;
    const int nq   = lane >> 4;
    const int bh   = blockIdx.x >> 6;
    const int kc   = blockIdx.x & 63;
    const int b = bh >> 3, hh = bh & 7;
    const int d  = w * 16 + dl;
    const int n0 = nq * 8;
    const int ch = bh * 64 + d;
    const int s0 = kc * TW;

    const int base_ud = b * (S_LEN * 512) + hh * 64;
    const int bB      = b * (S_LEN * 256) + hh * 32 + s0 * 256;

    // ---- cooperative stage ----
    {
        const int rB = tid >> 3, cB = tid & 7;
        *(float4*)&lB[rB * 32 + cB * 4] =
            *(const float4*)(Bp + bB + rB * 256 + cB * 4);
#pragma unroll
        for (int it = 0; it < 2; ++it) {
            const int idx = it * 256 + tid;
            const int r = idx >> 4, c = idx & 15;
            const int g = base_ud + (s0 + r) * 512 + c * 4;
            *(float4*)&ldt[r * 64 + c * 4] = *(const float4*)(dtp + g);
            *(float4*)&lu [r * 64 + c * 4] = *(const float4*)(up  + g);
        }
    }

    v2f Aneg2[4];
    {
        const float* Arow = Ap + (hh * D_DIM + d) * N_DIM + n0;
#pragma unroll
        for (int j = 0; j < 4; ++j) {
            v2f a2 = *(const v2f*)(Arow + 2 * j);
            Aneg2[j] = a2 * NLOG2E;
        }
    }

    __syncthreads();

    v2f bA2[4];
#pragma unroll
    for (int j = 0; j < 4; ++j) bA2[j] = (v2f)(0.0f);
    float sdt = 0.0f;

#pragma unroll 8
    for (int tt = 0; tt < TW; ++tt) {
        const float dtv = ldt[tt * 64 + d];
        const float uv  = lu [tt * 64 + d];
        const float kk  = dtv * uv;
        sdt += dtv;
        const v2f dt2 = (v2f)(dtv);
        const v2f kk2 = (v2f)(kk);
#pragma unroll
        for (int j = 0; j < 4; ++j) {
            const v2f B2 = *(const v2f*)&lB[tt * 32 + n0 + 2 * j];
            const v2f arg = dt2 * Aneg2[j];
            v2f e;
            e.x = __builtin_amdgcn_exp2f(arg.x);
            e.y = __builtin_amdgcn_exp2f(arg.y);
            bA2[j] = vfma(e, bA2[j], kk2 * B2);
        }
    }

    if (nq == 0) sdtb[kc * 1024 + ch] = sdt;
    {
        float* dst = bagg + (size_t)kc * 32768 + ch * 32 + n0;
        *(float4*)(dst + 0) = make_float4(bA2[0].x, bA2[0].y, bA2[1].x, bA2[1].y);
        *(float4*)(dst + 4) = make_float4(bA2[2].x, bA2[2].y, bA2[3].x, bA2[3].y);
    }
}

// K2: thread T = seg*32768 + ch*32 + n  (seg slow -> waves fully coalesced).
// Each thread scans its 16-chunk segment in registers, then the 4 segment
// transforms for a given (ch,n) are combined through a small ws buffer
// (segagg) written by all segs and read by all segs after one kernel-internal
// pass is impossible -> instead each thread computes its own exclusive
// prefix by re-reading the OTHER segments' transforms from segagg written
// in this same kernel? Cross-block dependency — not allowed. So: compose
// via shuffle by having each thread ALSO scan using lane-local data is not
// possible with seg-slow mapping. Resolution: each thread scans all 4
// segment transforms itself — the per-segment (Aseg,bseg) are cheap to
// rebuild: thread t loads its own segment fully (16 a,b pairs) AND the
// 3 other segments' precomputed transforms are not available...
// => Simplest correct coalesced design: each thread owns (ch,n) ENTIRELY
// (32768 threads), walks all 64 chunks in registers — unrolled, fully
// coalesced (adjacent threads = adjacent n), chain length 64 but all loads
// prefetched into registers up front (64+64 independent loads), then pure
// FMA chain. 128 waves/CU-equivalent occupancy: 32768 threads = 512 waves
// = 2 waves/CU — low, but the loads are all independent and issued before
// the chain; chain = 64 fma + 64 exp2 ≈ 1.5k cycles.
__global__ __launch_bounds__(256) void ssm_k2(
    const float* __restrict__ sdtb, const float* __restrict__ bagg,
    const float* __restrict__ Ap,   float* __restrict__ pref)
{
    const int T  = blockIdx.x * 256 + threadIdx.x;   // 32768 threads = (ch, n)
    const int n  = T & 31;
    const int ch = T >> 5;
    const int d  = ch & 63;
    const int hh = (ch >> 6) & 7;
    const float Aneg1 = NLOG2E * Ap[(hh * D_DIM + d) * N_DIM + n];

    const size_t base = (size_t)ch * 32 + n;

    float p = 0.0f;
#pragma unroll
    for (int k0 = 0; k0 < NKC; k0 += 16) {
        float bb[16], av[16];
#pragma unroll
        for (int i = 0; i < 16; ++i) {
            bb[i] = bagg[(size_t)(k0 + i) * 32768 + base];
            av[i] = sdtb[(k0 + i) * 1024 + ch];
        }
#pragma unroll
        for (int i = 0; i < 16; ++i)
            av[i] = __builtin_amdgcn_exp2f(Aneg1 * av[i]);
#pragma unroll
        for (int i = 0; i < 16; ++i) {
            pref[(size_t)(k0 + i) * 32768 + base] = p;
            p = fmaf(av[i], p, bb[i]);
        }
    }
}

__global__ __launch_bounds__(256) void ssm_k3(
    const float* __restrict__ dtp, const float* __restrict__ up,
    const float* __restrict__ Ap,  const float* __restrict__ Bp,
    const float* __restrict__ Cp,  const float* __restrict__ Dp,
    const float* __restrict__ pref, float* __restrict__ outp)
{
    __shared__ float ldt[TW * 64];        // 8 KB
    __shared__ float lu [TW * 64];        // 8 KB
    __shared__ float lB [TW * 32];        // 4 KB
    __shared__ float lC [TW * 32];        // 4 KB

    const int tid  = threadIdx.x;
    const int w    = tid >> 6;
    const int lane = tid & 63;
    const int dl   = lane & 15;
    const int nq   = lane >> 4;
    const int bh   = blockIdx.x >> 6;
    const int kc   = blockIdx.x & 63;
    const int b = bh >> 3, hh = bh & 7;
    const int d  = w * 16 + dl;
    const int n0 = nq * 8;
    const int ch = bh * 64 + d;
    const int s0 = kc * TW;

    const int base_ud = b * (S_LEN * 512) + hh * 64;
    const int bB      = b * (S_LEN * 256) + hh * 32 + s0 * 256;

    // ---- cooperative stage ----
    {
        const int rB = tid >> 3, cB = tid & 7;
        *(float4*)&lB[rB * 32 + cB * 4] =
            *(const float4*)(Bp + bB + rB * 256 + cB * 4);
        *(float4*)&lC[rB * 32 + cB * 4] =
            *(const float4*)(Cp + bB + rB * 256 + cB * 4);
#pragma unroll
        for (int it = 0; it < 2; ++it) {
            const int idx = it * 256 + tid;
            const int r = idx >> 4, c = idx & 15;
            const int g = base_ud + (s0 + r) * 512 + c * 4;
            *(float4*)&ldt[r * 64 + c * 4] = *(const float4*)(dtp + g);
            *(float4*)&lu [r * 64 + c * 4] = *(const float4*)(up  + g);
        }
    }

    // ---- entering state ----
    v2f h2[4];
    {
        const float* ps = pref + (size_t)kc * 32768 + ch * 32 + n0;
        float4 v0 = *(const float4*)(ps + 0);
        float4 v1 = *(const float4*)(ps + 4);
        h2[0].x = v0.x; h2[0].y = v0.y; h2[1].x = v0.z; h2[1].y = v0.w;
        h2[2].x = v1.x; h2[2].y = v1.y; h2[3].x = v1.z; h2[3].y = v1.w;
    }

    v2f Aneg2[4];
    {
        const float* Arow = Ap + (hh * D_DIM + d) * N_DIM + n0;
#pragma unroll
        for (int j = 0; j < 4; ++j) {
            v2f a2 = *(const v2f*)(Arow + 2 * j);
            Aneg2[j] = a2 * NLOG2E;
        }
    }

    const float Dv = Dp[hh];

    __syncthreads();

#pragma unroll 8
    for (int tt = 0; tt < TW; ++tt) {
        const float dtv = ldt[tt * 64 + d];
        const float uv  = lu [tt * 64 + d];
        const float kk  = dtv * uv;
        const v2f dt2 = (v2f)(dtv);
        const v2f kk2 = (v2f)(kk);
        v2f ya = (v2f)(0.0f);
        v2f yb = (v2f)(0.0f);
#pragma unroll
        for (int j = 0; j < 4; ++j) {
            const v2f B2 = *(const v2f*)&lB[tt * 32 + n0 + 2 * j];
            const v2f C2 = *(const v2f*)&lC[tt * 32 + n0 + 2 * j];
            const v2f arg = dt2 * Aneg2[j];
            v2f e;
            e.x = __builtin_amdgcn_exp2f(arg.x);
            e.y = __builtin_amdgcn_exp2f(arg.y);
            h2[j] = vfma(e, h2[j], kk2 * B2);
            if (j & 1) yb = vfma(h2[j], C2, yb);
            else       ya = vfma(h2[j], C2, ya);
        }
        float y = (ya.x + ya.y) + (yb.x + yb.y);
        y += __shfl_xor(y, 16);
        y += __shfl_xor(y, 32);
        if (nq == 0) outp[base_ud + d + (s0 + tt) * 512] = fmaf(Dv, uv, y);
    }
}

} // namespace

extern "C" void kernel_launch(void* const* d_in, const int* in_sizes, int n_in,
                              void* d_out, int out_size, void* d_ws, size_t ws_size,
                              hipStream_t stream)
{
    const float* u  = (const float*)d_in[0];
    const float* dt = (const float*)d_in[1];
    const float* A  = (const float*)d_in[2];
    const float* B  = (const float*)d_in[3];
    const float* C  = (const float*)d_in[4];
    const float* D  = (const float*)d_in[5];
    float* out = (float*)d_out;

    float* sdtb = (float*)d_ws;                         // 0.25 MB
    float* bagg = sdtb + (size_t)NKC * 1024;            // 8.4 MB
    float* pref = bagg + (size_t)NKC * 32 * 1024;       // 8.4 MB

    ssm_k1<<<dim3(16 * NKC), dim3(256), 0, stream>>>(dt, u, A, B, sdtb, bagg);
    ssm_k2<<<dim3(128),      dim3(256), 0, stream>>>(sdtb, bagg, A, pref);
    ssm_k3<<<dim3(16 * NKC), dim3(256), 0, stream>>>(dt, u, A, B, C, D, pref, out);
}

// Round 24
// 38.840 us; speedup vs baseline: 5.6641x; 1.0575x over previous
//
#include <hip/hip_runtime.h>

namespace {

typedef float v2f __attribute__((ext_vector_type(2)));

__device__ __forceinline__ v2f vfma(v2f a, v2f b, v2f c) {
#if __has_builtin(__builtin_elementwise_fma)
    return __builtin_elementwise_fma(a, b, c);
#else
    v2f r; r.x = fmaf(a.x, b.x, c.x); r.y = fmaf(a.y, b.y, c.y); return r;
#endif
}

// bf16 helpers (RNE pack, shift unpack) — no hand-rolled VOP3P (R20 lesson).
__device__ __forceinline__ unsigned short f2bf(float f) {
    unsigned int x = __float_as_uint(f);
    return (unsigned short)((x + 0x7fffu + ((x >> 16) & 1u)) >> 16);
}
__device__ __forceinline__ float bf2f_lo(unsigned int u) {   // low 16 bits
    return __uint_as_float(u << 16);
}
__device__ __forceinline__ float bf2f_hi(unsigned int u) {   // high 16 bits
    return __uint_as_float(u & 0xffff0000u);
}

constexpr int S_LEN = 2048;
constexpr int H_N   = 8;
constexpr int D_DIM = 64;
constexpr int N_DIM = 32;
constexpr int TW    = 32;             // timesteps per chunk
constexpr int NKC   = S_LEN / TW;     // 64 chunks per (b,h)
constexpr float NLOG2E = -1.4426950408889634f;

// ws:
//   sdtb: f32  [kc][ch]      64*1024          (0.25 MB) — sum of dt over chunk
//   bagg: bf16 [kc][ch][n]   64*1024*32*2B    (4.2 MB)  — chunk b-aggregate
//   pref: bf16 [kc][ch][n]   64*1024*32*2B    (4.2 MB)  — state entering chunk
// bf16 ws halves intermediate traffic (was 33.6 MB r+w in f32); accuracy
// budget ~1 absmax vs 3.54 threshold.
// K1/K3: R21/R23 structure — 256 thr = 4 waves = ONE chunk; wave w:
//   d = w*16+(lane&15), nq = lane>>4, n0 = nq*8; full cooperative LDS
//   staging of dt/u/B/C (one barrier); packed-fp32 <2 x float> inner math.
// K2: thread = (ch, n), full 64-chunk register walk, fully coalesced
//   (adjacent lanes = adjacent n; 128 B/wave in bf16).

__global__ __launch_bounds__(256) void ssm_k1(
    const float* __restrict__ dtp, const float* __restrict__ up,
    const float* __restrict__ Ap,  const float* __restrict__ Bp,
    float* __restrict__ sdtb, unsigned short* __restrict__ bagg)
{
    __shared__ float ldt[TW * 64];        // 8 KB [t][d]
    __shared__ float lu [TW * 64];        // 8 KB
    __shared__ float lB [TW * 32];        // 4 KB [t][n]

    const int tid  = threadIdx.x;
    const int w    = tid >> 6;
    const int lane = tid & 63;
    const int dl   = lane & 15;
    const int nq   = lane >> 4;
    const int bh   = blockIdx.x >> 6;
    const int kc   = blockIdx.x & 63;
    const int b = bh >> 3, hh = bh & 7;
    const int d  = w * 16 + dl;
    const int n0 = nq * 8;
    const int ch = bh * 64 + d;
    const int s0 = kc * TW;

    const int base_ud = b * (S_LEN * 512) + hh * 64;
    const int bB      = b * (S_LEN * 256) + hh * 32 + s0 * 256;

    // ---- cooperative stage ----
    {
        const int rB = tid >> 3, cB = tid & 7;
        *(float4*)&lB[rB * 32 + cB * 4] =
            *(const float4*)(Bp + bB + rB * 256 + cB * 4);
#pragma unroll
        for (int it = 0; it < 2; ++it) {
            const int idx = it * 256 + tid;
            const int r = idx >> 4, c = idx & 15;
            const int g = base_ud + (s0 + r) * 512 + c * 4;
            *(float4*)&ldt[r * 64 + c * 4] = *(const float4*)(dtp + g);
            *(float4*)&lu [r * 64 + c * 4] = *(const float4*)(up  + g);
        }
    }

    v2f Aneg2[4];
    {
        const float* Arow = Ap + (hh * D_DIM + d) * N_DIM + n0;
#pragma unroll
        for (int j = 0; j < 4; ++j) {
            v2f a2 = *(const v2f*)(Arow + 2 * j);
            Aneg2[j] = a2 * NLOG2E;
        }
    }

    __syncthreads();

    v2f bA2[4];
#pragma unroll
    for (int j = 0; j < 4; ++j) bA2[j] = (v2f)(0.0f);
    float sdt = 0.0f;

#pragma unroll 8
    for (int tt = 0; tt < TW; ++tt) {
        const float dtv = ldt[tt * 64 + d];
        const float uv  = lu [tt * 64 + d];
        const float kk  = dtv * uv;
        sdt += dtv;
        const v2f dt2 = (v2f)(dtv);
        const v2f kk2 = (v2f)(kk);
#pragma unroll
        for (int j = 0; j < 4; ++j) {
            const v2f B2 = *(const v2f*)&lB[tt * 32 + n0 + 2 * j];
            const v2f arg = dt2 * Aneg2[j];
            v2f e;
            e.x = __builtin_amdgcn_exp2f(arg.x);
            e.y = __builtin_amdgcn_exp2f(arg.y);
            bA2[j] = vfma(e, bA2[j], kk2 * B2);
        }
    }

    if (nq == 0) sdtb[kc * 1024 + ch] = sdt;
    {
        // pack 8 f32 -> 8 bf16 -> one uint4 (16B) store
        uint4 pk;
        pk.x = ((unsigned int)f2bf(bA2[0].y) << 16) | f2bf(bA2[0].x);
        pk.y = ((unsigned int)f2bf(bA2[1].y) << 16) | f2bf(bA2[1].x);
        pk.z = ((unsigned int)f2bf(bA2[2].y) << 16) | f2bf(bA2[2].x);
        pk.w = ((unsigned int)f2bf(bA2[3].y) << 16) | f2bf(bA2[3].x);
        *(uint4*)(bagg + (size_t)kc * 32768 + ch * 32 + n0) = pk;
    }
}

__global__ __launch_bounds__(256) void ssm_k2(
    const float* __restrict__ sdtb, const unsigned short* __restrict__ bagg,
    const float* __restrict__ Ap,   unsigned short* __restrict__ pref)
{
    const int T  = blockIdx.x * 256 + threadIdx.x;   // 32768 threads = (ch, n)
    const int n  = T & 31;
    const int ch = T >> 5;
    const int d  = ch & 63;
    const int hh = (ch >> 6) & 7;
    const float Aneg1 = NLOG2E * Ap[(hh * D_DIM + d) * N_DIM + n];

    const size_t base = (size_t)ch * 32 + n;

    float p = 0.0f;
#pragma unroll
    for (int k0 = 0; k0 < NKC; k0 += 16) {
        float bb[16], av[16];
#pragma unroll
        for (int i = 0; i < 16; ++i) {
            bb[i] = bf2f_lo(bagg[(size_t)(k0 + i) * 32768 + base]);
            av[i] = sdtb[(k0 + i) * 1024 + ch];
        }
#pragma unroll
        for (int i = 0; i < 16; ++i)
            av[i] = __builtin_amdgcn_exp2f(Aneg1 * av[i]);
#pragma unroll
        for (int i = 0; i < 16; ++i) {
            pref[(size_t)(k0 + i) * 32768 + base] = f2bf(p);
            p = fmaf(av[i], p, bb[i]);
        }
    }
}

__global__ __launch_bounds__(256) void ssm_k3(
    const float* __restrict__ dtp, const float* __restrict__ up,
    const float* __restrict__ Ap,  const float* __restrict__ Bp,
    const float* __restrict__ Cp,  const float* __restrict__ Dp,
    const unsigned short* __restrict__ pref, float* __restrict__ outp)
{
    __shared__ float ldt[TW * 64];        // 8 KB
    __shared__ float lu [TW * 64];        // 8 KB
    __shared__ float lB [TW * 32];        // 4 KB
    __shared__ float lC [TW * 32];        // 4 KB

    const int tid  = threadIdx.x;
    const int w    = tid >> 6;
    const int lane = tid & 63;
    const int dl   = lane & 15;
    const int nq   = lane >> 4;
    const int bh   = blockIdx.x >> 6;
    const int kc   = blockIdx.x & 63;
    const int b = bh >> 3, hh = bh & 7;
    const int d  = w * 16 + dl;
    const int n0 = nq * 8;
    const int ch = bh * 64 + d;
    const int s0 = kc * TW;

    const int base_ud = b * (S_LEN * 512) + hh * 64;
    const int bB      = b * (S_LEN * 256) + hh * 32 + s0 * 256;

    // ---- cooperative stage ----
    {
        const int rB = tid >> 3, cB = tid & 7;
        *(float4*)&lB[rB * 32 + cB * 4] =
            *(const float4*)(Bp + bB + rB * 256 + cB * 4);
        *(float4*)&lC[rB * 32 + cB * 4] =
            *(const float4*)(Cp + bB + rB * 256 + cB * 4);
#pragma unroll
        for (int it = 0; it < 2; ++it) {
            const int idx = it * 256 + tid;
            const int r = idx >> 4, c = idx & 15;
            const int g = base_ud + (s0 + r) * 512 + c * 4;
            *(float4*)&ldt[r * 64 + c * 4] = *(const float4*)(dtp + g);
            *(float4*)&lu [r * 64 + c * 4] = *(const float4*)(up  + g);
        }
    }

    // ---- entering state: one uint4 = 8 bf16 ----
    v2f h2[4];
    {
        uint4 v = *(const uint4*)(pref + (size_t)kc * 32768 + ch * 32 + n0);
        h2[0].x = bf2f_lo(v.x); h2[0].y = bf2f_hi(v.x);
        h2[1].x = bf2f_lo(v.y); h2[1].y = bf2f_hi(v.y);
        h2[2].x = bf2f_lo(v.z); h2[2].y = bf2f_hi(v.z);
        h2[3].x = bf2f_lo(v.w); h2[3].y = bf2f_hi(v.w);
    }

    v2f Aneg2[4];
    {
        const float* Arow = Ap + (hh * D_DIM + d) * N_DIM + n0;
#pragma unroll
        for (int j = 0; j < 4; ++j) {
            v2f a2 = *(const v2f*)(Arow + 2 * j);
            Aneg2[j] = a2 * NLOG2E;
        }
    }

    const float Dv = Dp[hh];

    __syncthreads();

#pragma unroll 8
    for (int tt = 0; tt < TW; ++tt) {
        const float dtv = ldt[tt * 64 + d];
        const float uv  = lu [tt * 64 + d];
        const float kk  = dtv * uv;
        const v2f dt2 = (v2f)(dtv);
        const v2f kk2 = (v2f)(kk);
        v2f ya = (v2f)(0.0f);
        v2f yb = (v2f)(0.0f);
#pragma unroll
        for (int j = 0; j < 4; ++j) {
            const v2f B2 = *(const v2f*)&lB[tt * 32 + n0 + 2 * j];
            const v2f C2 = *(const v2f*)&lC[tt * 32 + n0 + 2 * j];
            const v2f arg = dt2 * Aneg2[j];
            v2f e;
            e.x = __builtin_amdgcn_exp2f(arg.x);
            e.y = __builtin_amdgcn_exp2f(arg.y);
            h2[j] = vfma(e, h2[j], kk2 * B2);
            if (j & 1) yb = vfma(h2[j], C2, yb);
            else       ya = vfma(h2[j], C2, ya);
        }
        float y = (ya.x + ya.y) + (yb.x + yb.y);
        y += __shfl_xor(y, 16);
        y += __shfl_xor(y, 32);
        if (nq == 0) outp[base_ud + d + (s0 + tt) * 512] = fmaf(Dv, uv, y);
    }
}

} // namespace

extern "C" void kernel_launch(void* const* d_in, const int* in_sizes, int n_in,
                              void* d_out, int out_size, void* d_ws, size_t ws_size,
                              hipStream_t stream)
{
    const float* u  = (const float*)d_in[0];
    const float* dt = (const float*)d_in[1];
    const float* A  = (const float*)d_in[2];
    const float* B  = (const float*)d_in[3];
    const float* C  = (const float*)d_in[4];
    const float* D  = (const float*)d_in[5];
    float* out = (float*)d_out;

    float* sdtb = (float*)d_ws;                                     // 0.25 MB
    unsigned short* bagg = (unsigned short*)(sdtb + (size_t)NKC * 1024);   // 4.2 MB
    unsigned short* pref = bagg + (size_t)NKC * 32 * 1024;                 // 4.2 MB

    ssm_k1<<<dim3(16 * NKC), dim3(256), 0, stream>>>(dt, u, A, B, sdtb, bagg);
    ssm_k2<<<dim3(128),      dim3(256), 0, stream>>>(sdtb, bagg, A, pref);
    ssm_k3<<<dim3(16 * NKC), dim3(256), 0, stream>>>(dt, u, A, B, C, D, pref, out);
}